// Round 18
// baseline (249.342 us; speedup 1.0000x reference)
//
#include <hip/hip_runtime.h>
#include <math.h>

constexpr int Bb = 4, Ss = 2048, Dd = 1024, Hh = 16, HDd = 64;

typedef __attribute__((ext_vector_type(8))) short short8;
typedef __attribute__((ext_vector_type(4))) float floatx4;
typedef __attribute__((ext_vector_type(16))) float floatx16;
typedef __attribute__((ext_vector_type(4))) unsigned int uint4v;

__device__ inline unsigned short bf16r(float f) {
    unsigned int u = __builtin_bit_cast(unsigned int, f);
    u += 0x7fffu + ((u >> 16) & 1u);
    return (unsigned short)(u >> 16);
}
// HW packed cvt (RNE, bit-identical to manual round)
__device__ inline unsigned int cvtpk(float lo, float hi) {
    unsigned int r;
    asm("v_cvt_pk_bf16_f32 %0, %1, %2" : "=v"(r) : "v"(lo), "v"(hi));
    return r;
}

__device__ inline void gld16(const void* g, void* l) {
    __builtin_amdgcn_global_load_lds((const __attribute__((address_space(1))) void*)g,
                                     (__attribute__((address_space(3))) void*)l, 16, 0, 0);
}

__device__ inline floatx4 mfma16(short8 a, short8 b, floatx4 c) {
    return __builtin_amdgcn_mfma_f32_16x16x32_bf16(a, b, c, 0, 0, 0);
}
__device__ inline floatx16 mfma32(short8 a, short8 b, floatx16 c) {
    return __builtin_amdgcn_mfma_f32_32x32x16_bf16(a, b, c, 0, 0, 0);
}

// log2(e) folded into Wq/bq so attn can use native exp2 directly.
#define LOG2E 1.4426950408889634f
#define EXP2_SHIFT 17.312340490667562f   // 12 * log2(e)

// ---------------------------------------------------------------------------
// Weight transpose + bf16 convert: Wt[z][n][k] = W_z[k][n] * scale_z
// ---------------------------------------------------------------------------
__global__ __launch_bounds__(256)
void conv_w_kernel(const float* __restrict__ Wq, const float* __restrict__ Wk,
                   const float* __restrict__ Wv, const float* __restrict__ Wo,
                   unsigned short* __restrict__ Wt)
{
    int z = blockIdx.z;
    const float* W = z == 0 ? Wq : z == 1 ? Wk : z == 2 ? Wv : Wo;
    float scale = z == 0 ? 0.125f * LOG2E : 1.0f;
    unsigned short* out = Wt + (size_t)z * 1024 * 1024;

    int r0 = blockIdx.x * 64;
    int c0 = blockIdx.y * 64;
    int t = threadIdx.x;
    int oc = (t & 3) * 16;
    int orow = c0 + (t >> 2);

    float v[16];
    #pragma unroll
    for (int j = 0; j < 16; ++j)
        v[j] = W[(size_t)(r0 + oc + j) * 1024 + orow] * scale;

    unsigned int pk[8];
    #pragma unroll
    for (int j = 0; j < 8; ++j) pk[j] = cvtpk(v[2 * j], v[2 * j + 1]);

    uint4v w0 = {pk[0], pk[1], pk[2], pk[3]};
    uint4v w1 = {pk[4], pk[5], pk[6], pk[7]};
    *(uint4v*)(out + (size_t)orow * 1024 + r0 + oc) = w0;
    *(uint4v*)(out + (size_t)orow * 1024 + r0 + oc + 8) = w1;
}

__global__ __launch_bounds__(256)
void conv_bias_kernel(const float* __restrict__ bq, float* __restrict__ bqs)
{
    int idx = blockIdx.x * 256 + threadIdx.x;
    if (idx < 1024) bqs[idx] = bq[idx] * 0.125f * LOG2E;
}

// ---------------------------------------------------------------------------
// QKV projection GEMM v6 — race-free single-barrier pipeline with FULL
// prefetch distance:
//   Per iter: FENCE(vmcnt(8) lgkmcnt(0)) -> ISSUEB(kt+2) -> ISSUEA(kt+2)
//             -> COMP(kt).
//   ISSUEA(kt+2) overwrites Aa[(kt+2)%3] = Aa[(kt-1)%3], whose last readers
//   (COMP(kt-1)) drained at fence(kt) via lgkmcnt(0)+barrier -> safe.
//   A issued at TOP of iter kt, needed at fence(kt+2): 2 full iterations of
//   latency cover (the v5 regression had only 1).
//   B register sets period 3 (bB0/1/2) since ISSUEB(kt+2) precedes COMP(kt).
//   vmcnt(8): outstanding at fence = B(kt)4+A(kt)4 (oldest) + B(kt+1)4+A(kt+1)4.
//   LDS = 48KB (3 A buffers) -> 3 blocks/CU.
// ---------------------------------------------------------------------------
__global__ __launch_bounds__(256)
void qkv_gemm_kernel(const float* __restrict__ qin, const float* __restrict__ kin,
                     const float* __restrict__ vin,
                     const unsigned short* __restrict__ Wt,
                     const float* __restrict__ bqs, const float* __restrict__ bk,
                     const float* __restrict__ bv,
                     unsigned short* __restrict__ Qb, unsigned short* __restrict__ Kb,
                     unsigned short* __restrict__ Vb)
{
    int z = blockIdx.z;
    const float* A = z == 0 ? qin : z == 1 ? kin : vin;
    const unsigned short* W = Wt + (size_t)z * 1048576;
    const float* bias = z == 0 ? bqs : z == 1 ? bk : bv;
    unsigned short* O = z == 0 ? Qb : z == 1 ? Kb : Vb;

    __shared__ __align__(16) char qsm[49152];
    char* Aa0 = qsm;                 // A fp32 [128][32], swizzled, 16KB each
    char* Aa1 = qsm + 16384;
    char* Aa2 = qsm + 32768;

    int tid = threadIdx.x, lane = tid & 63, w = tid >> 6;
    int wr = w >> 1, wc = w & 1;
    int fr = lane & 15, fg = lane >> 4;
    int m0 = blockIdx.x * 128, n0 = blockIdx.y * 128;

    // A staging geometry (R15-verified): chunk j fills rows w*32+j*8+(lane>>3);
    // source k pre-swizzled so linear DMA lands XOR-swizzled in LDS.
    int arow_base = w * 32 + (lane >> 3);
    int asrc_col = (((lane & 7) ^ ((lane >> 3) & 7)) << 4) >> 2;  // fp32 elems

    // B fragment base: row n0 + wc*64 + ni*16 + fr, col kt*32 + fg*8 (bf16)
    const unsigned short* Wfrag = W + (size_t)(n0 + wc * 64 + fr) * 1024 + fg * 8;

    floatx4 acc[4][4] = {};
    uint4v bB0[4], bB1[4], bB2[4];

#define ISSUEA(kt, dst) {                                                       \
    _Pragma("unroll")                                                           \
    for (int j_ = 0; j_ < 4; ++j_) {                                            \
        const float* g_ = A + (size_t)(m0 + arow_base + j_ * 8) * 1024          \
                            + (kt) * 32 + asrc_col;                             \
        gld16(g_, (dst) + (size_t)((w << 8) + (j_ << 6) + lane) * 16);          \
    }}
#define ISSUEB(kt, br) {                                                        \
    _Pragma("unroll")                                                           \
    for (int ni_ = 0; ni_ < 4; ++ni_)                                           \
        br[ni_] = *(const uint4v*)(Wfrag + (size_t)(ni_ * 16) * 1024 + (kt) * 32); }
#define COMP(Ac, br) { short8 af_[4], bf_[4];                                   \
    _Pragma("unroll")                                                           \
    for (int mi = 0; mi < 4; ++mi) {                                            \
        int row_ = wr * 64 + mi * 16 + fr;                                      \
        int xb_ = (row_ & 7) << 4;                                              \
        floatx4 al_ = *(const floatx4*)((Ac) + row_ * 128 + ((fg * 32) ^ xb_)); \
        floatx4 ah_ = *(const floatx4*)((Ac) + row_ * 128 + ((fg * 32 + 16) ^ xb_)); \
        uint4v u_ = {cvtpk(al_[0], al_[1]), cvtpk(al_[2], al_[3]),              \
                     cvtpk(ah_[0], ah_[1]), cvtpk(ah_[2], ah_[3])};             \
        af_[mi] = __builtin_bit_cast(short8, u_);                               \
    }                                                                           \
    _Pragma("unroll")                                                           \
    for (int ni = 0; ni < 4; ++ni) bf_[ni] = __builtin_bit_cast(short8, br[ni]); \
    _Pragma("unroll")                                                           \
    for (int mi = 0; mi < 4; ++mi)                                              \
        _Pragma("unroll")                                                       \
        for (int ni = 0; ni < 4; ++ni)                                          \
            acc[mi][ni] = mfma16(af_[mi], bf_[ni], acc[mi][ni]); }
#define FV8  { asm volatile("s_waitcnt vmcnt(8) lgkmcnt(0)" ::: "memory");      \
    __builtin_amdgcn_s_barrier(); __builtin_amdgcn_sched_barrier(0); }
#define FV0  { asm volatile("s_waitcnt vmcnt(0) lgkmcnt(0)" ::: "memory");      \
    __builtin_amdgcn_s_barrier(); __builtin_amdgcn_sched_barrier(0); }

    // prologue: B(0), A(0), B(1), A(1) in flight (16 ops, oldest 8 = B0,A0)
    ISSUEB(0, bB0); ISSUEA(0, Aa0); ISSUEB(1, bB1); ISSUEA(1, Aa1);

    // main loop: kt = 0..29 (issue targets kt+2 = 2..31); period 3 on A and B
    for (int p = 0; p < 5; ++p) {
        int kt = 6 * p;
        FV8; ISSUEB(kt + 2, bB2); ISSUEA(kt + 2, Aa2); COMP(Aa0, bB0);   // kt
        FV8; ISSUEB(kt + 3, bB0); ISSUEA(kt + 3, Aa0); COMP(Aa1, bB1);   // kt+1
        FV8; ISSUEB(kt + 4, bB1); ISSUEA(kt + 4, Aa1); COMP(Aa2, bB2);   // kt+2
        FV8; ISSUEB(kt + 5, bB2); ISSUEA(kt + 5, Aa2); COMP(Aa0, bB0);   // kt+3
        FV8; ISSUEB(kt + 6, bB0); ISSUEA(kt + 6, Aa0); COMP(Aa1, bB1);   // kt+4
        FV8; ISSUEB(kt + 7, bB1); ISSUEA(kt + 7, Aa1); COMP(Aa2, bB2);   // kt+5
    }

    // epilogue: kt = 30 (Aa0, bB0), kt = 31 (Aa1, bB1)
    FV8; COMP(Aa0, bB0);
    FV0; COMP(Aa1, bB1);
    __syncthreads();

#undef ISSUEA
#undef ISSUEB
#undef COMP
#undef FV8
#undef FV0

    float bvv[4];
    #pragma unroll
    for (int ni = 0; ni < 4; ++ni) bvv[ni] = bias[n0 + wc * 64 + ni * 16 + fr];

    if (z == 2) {
        // Per-wave transpose tile T[64 hd][72 pad] bf16, reusing staging LDS.
        unsigned short* T = (unsigned short*)(qsm) + (size_t)w * 4608;
        #pragma unroll
        for (int mi = 0; mi < 4; ++mi)
            #pragma unroll
            for (int ni = 0; ni < 4; ++ni) {
                int hdl = ni * 16 + fr;
                int sl  = mi * 16 + fg * 4;
                uint2 u2;
                u2.x = cvtpk(acc[mi][ni][0] + bvv[ni], acc[mi][ni][1] + bvv[ni]);
                u2.y = cvtpk(acc[mi][ni][2] + bvv[ni], acc[mi][ni][3] + bvv[ni]);
                *(uint2*)(T + hdl * 72 + sl) = u2;
            }
        __syncthreads();
        int h  = (n0 + wc * 64) >> 6;
        int Ms = m0 + wr * 64;
        int b_ = Ms >> 11, sbase = Ms & 2047;
        unsigned short* Od = O + (((size_t)(b_ * 16 + h) * 64) << 11) + sbase;
        int rg = lane >> 3, sc = lane & 7;
        #pragma unroll
        for (int j = 0; j < 8; ++j) {
            int row = j * 8 + rg;
            uint4v t = *(const uint4v*)(T + row * 72 + sc * 8);
            *(uint4v*)(Od + ((size_t)row << 11) + sc * 8) = t;
        }
    } else {
        #pragma unroll
        for (int mi = 0; mi < 4; ++mi)
            #pragma unroll
            for (int ni = 0; ni < 4; ++ni) {
                int n = n0 + wc * 64 + ni * 16 + fr;
                int h = n >> 6, hd = n & 63;
                #pragma unroll
                for (int i = 0; i < 4; ++i) {
                    int m = m0 + wr * 64 + mi * 16 + fg * 4 + i;
                    int b_ = m >> 11, s = m & 2047;
                    float val = acc[mi][ni][i] + bvv[ni];
                    O[(((size_t)(b_ * 16 + h) * 2048 + s) << 6) + hd] = bf16r(val);
                }
            }
    }
}

// ---------------------------------------------------------------------------
// Flash attention + XCD-chunk remap (unchanged from round 15)
// ---------------------------------------------------------------------------
__global__ __launch_bounds__(256)
void attn_kernel(const unsigned short* __restrict__ Qb, const unsigned short* __restrict__ Kb,
                 const unsigned short* __restrict__ Vtb, unsigned short* __restrict__ Xb)
{
    __shared__ __align__(16) char smem[32768];

    int pphys = blockIdx.x + (blockIdx.y << 4) + (blockIdx.z << 8);   // 0..1023
    int L = (pphys & 7) * 128 + (pphys >> 3);
    int qt = L & 15;
    int h  = (L >> 4) & 15;
    int b  = L >> 8;

    int tid = threadIdx.x, lane = tid & 63, w = tid >> 6;
    int c = lane & 31, hi = lane >> 5;
    int q0 = qt * 128;
    size_t base = ((size_t)(b * 16 + h)) * 2048 * 64;
    const unsigned short* Qp = Qb + base + (size_t)(q0 + w * 32) * 64;
    const unsigned short* Kp = Kb + base;
    const unsigned short* Vp = Vtb + base;

    short8 qfr[4];
    #pragma unroll
    for (int ks = 0; ks < 4; ++ks)
        qfr[ks] = *(const short8*)(Qp + (size_t)c * 64 + ks * 16 + hi * 8);

    floatx16 acc_o[2] = {};
    floatx16 acc_l = {};
    uint4v onesu = {0x3F803F80u, 0x3F803F80u, 0x3F803F80u, 0x3F803F80u};
    short8 onesb = __builtin_bit_cast(short8, onesu);

    int p0 = tid & 7;
    int r0 = tid >> 3;
    int r1 = r0 + 32;
    int g0 = p0 ^ (r0 & 7);

    auto STAGE = [&](int kt, char* Kd, char* Vd) {
        gld16(Kp + ((size_t)(kt * 64 + r0) << 6) + g0 * 8, Kd + (size_t)tid * 16);
        gld16(Kp + ((size_t)(kt * 64 + r1) << 6) + g0 * 8, Kd + (size_t)(tid + 256) * 16);
        gld16(Vp + ((size_t)r0 << 11) + kt * 64 + g0 * 8, Vd + (size_t)tid * 16);
        gld16(Vp + ((size_t)r1 << 11) + kt * 64 + g0 * 8, Vd + (size_t)(tid + 256) * 16);
    };

    STAGE(0, smem, smem + 8192);
    __syncthreads();

    for (int kt = 0; kt < 32; ++kt) {
        char* Kl = smem + (kt & 1) * 16384;
        char* Vl = Kl + 8192;
        if (kt + 1 < 32) {
            char* Kn = smem + ((kt + 1) & 1) * 16384;
            STAGE(kt + 1, Kn, Kn + 8192);
        }

        #pragma unroll
        for (int kvt = 0; kvt < 2; ++kvt) {
            floatx16 st;
            #pragma unroll
            for (int r = 0; r < 16; ++r) st[r] = -EXP2_SHIFT;

            __builtin_amdgcn_s_setprio(1);
            #pragma unroll
            for (int ks = 0; ks < 4; ++ks) {
                int row = kvt * 32 + c;
                short8 kf = *(const short8*)(Kl + row * 128 +
                                             ((ks * 32 + hi * 16) ^ ((row & 7) << 4)));
                st = mfma32(kf, qfr[ks], st);
            }
            __builtin_amdgcn_s_setprio(0);

            float p[16];
            #pragma unroll
            for (int r = 0; r < 16; ++r)
                p[r] = __builtin_amdgcn_exp2f(st[r]);
            unsigned int j[8];
            #pragma unroll
            for (int t2 = 0; t2 < 8; ++t2)
                j[t2] = cvtpk(p[2 * t2], p[2 * t2 + 1]);
            asm volatile("v_permlane32_swap_b32 %0, %1" : "+v"(j[0]), "+v"(j[2]));
            asm volatile("v_permlane32_swap_b32 %0, %1" : "+v"(j[1]), "+v"(j[3]));
            asm volatile("v_permlane32_swap_b32 %0, %1" : "+v"(j[4]), "+v"(j[6]));
            asm volatile("v_permlane32_swap_b32 %0, %1" : "+v"(j[5]), "+v"(j[7]));
            uint4v pa0 = {j[0], j[1], j[2], j[3]};
            uint4v pa1 = {j[4], j[5], j[6], j[7]};
            short8 paA = __builtin_bit_cast(short8, pa0);
            short8 paB = __builtin_bit_cast(short8, pa1);

            __builtin_amdgcn_s_setprio(1);
            #pragma unroll
            for (int kvs2 = 0; kvs2 < 2; ++kvs2) {
                int kstep = kvt * 2 + kvs2;
                short8 pa = kvs2 ? paB : paA;
                #pragma unroll
                for (int dvt = 0; dvt < 2; ++dvt) {
                    int dv = dvt * 32 + c;
                    short8 vf = *(const short8*)(Vl + dv * 128 +
                                                 ((kstep * 32 + hi * 16) ^ ((dv & 7) << 4)));
                    acc_o[dvt] = mfma32(pa, vf, acc_o[dvt]);
                }
            }
            acc_l = mfma32(paA, onesb, acc_l);
            acc_l = mfma32(paB, onesb, acc_l);
            __builtin_amdgcn_s_setprio(0);
        }
        __syncthreads();
    }

    unsigned short* Ot = (unsigned short*)smem;

    #pragma unroll
    for (int r = 0; r < 16; ++r) {
        int rowq = (r & 3) + 8 * (r >> 2) + 4 * hi;
        float inv = 1.0f / acc_l[r];
        int ql = w * 32 + rowq;
        Ot[ql * 64 + c]      = bf16r(acc_o[0][r] * inv);
        Ot[ql * 64 + 32 + c] = bf16r(acc_o[1][r] * inv);
    }
    __syncthreads();

    {
        int row = tid >> 1, half = tid & 1;
        const unsigned short* src = Ot + row * 64 + half * 32;
        unsigned short* dst = Xb + ((size_t)b * 2048 + q0 + row) * 1024
                                 + h * 64 + half * 32;
        uint4v v0 = *(const uint4v*)(src);
        uint4v v1 = *(const uint4v*)(src + 8);
        uint4v v2 = *(const uint4v*)(src + 16);
        uint4v v3 = *(const uint4v*)(src + 24);
        *(uint4v*)(dst) = v0;
        *(uint4v*)(dst + 8) = v1;
        *(uint4v*)(dst + 16) = v2;
        *(uint4v*)(dst + 24) = v3;
    }
}

// ---------------------------------------------------------------------------
// Output projection GEMM (unchanged)
// ---------------------------------------------------------------------------
__global__ __launch_bounds__(256)
void out_gemm_kernel(const unsigned short* __restrict__ Xb,
                     const unsigned short* __restrict__ Wto,
                     const float* __restrict__ bo, float* __restrict__ out)
{
    __shared__ __align__(16) char osm[32768];
    unsigned short* Asm0 = (unsigned short*)(osm);
    unsigned short* Bsm0 = (unsigned short*)(osm + 8192);
    unsigned short* Asm1 = (unsigned short*)(osm + 16384);
    unsigned short* Bsm1 = (unsigned short*)(osm + 24576);

    int tid = threadIdx.x, lane = tid & 63, w = tid >> 6;
    int wr = w >> 1, wc = w & 1;
    int fr = lane & 15, fg = lane >> 4;
    int m0 = blockIdx.x * 128, n0 = blockIdx.y * 128;

    const int aRdo = (wr * 64 + fr) * 32 + fg * 8;
    const int bRdo = (wc * 64 + fr) * 32 + fg * 8;

    floatx4 acc[4][4] = {};

    auto STAGE = [&](int k0, unsigned short* Ad, unsigned short* Bd) {
        #pragma unroll
        for (int it = 0; it < 2; ++it) {
            int cA = tid + it * 256;
            const unsigned short* ga = Xb + (size_t)(m0 + (cA >> 2)) * 1024 + k0 + (cA & 3) * 8;
            gld16(ga, (char*)Ad + (size_t)(it * 256 + w * 64) * 16);
            const unsigned short* gb = Wto + (size_t)(n0 + (cA >> 2)) * 1024 + k0 + (cA & 3) * 8;
            gld16(gb, (char*)Bd + (size_t)(it * 256 + w * 64) * 16);
        }
    };

    STAGE(0, Asm0, Bsm0);
    __syncthreads();

    for (int kt = 0; kt < 32; ++kt) {
        unsigned short* Acur = (kt & 1) ? Asm1 : Asm0;
        unsigned short* Bcur = (kt & 1) ? Bsm1 : Bsm0;
        if (kt < 31)
            STAGE((kt + 1) * 32, (kt & 1) ? Asm0 : Asm1, (kt & 1) ? Bsm0 : Bsm1);

        short8 af[4], bf[4];
        #pragma unroll
        for (int mi = 0; mi < 4; ++mi) af[mi] = *(const short8*)(Acur + aRdo + mi * 16 * 32);
        #pragma unroll
        for (int ni = 0; ni < 4; ++ni) bf[ni] = *(const short8*)(Bcur + bRdo + ni * 16 * 32);
        #pragma unroll
        for (int mi = 0; mi < 4; ++mi)
            #pragma unroll
            for (int ni = 0; ni < 4; ++ni)
                acc[mi][ni] = mfma16(af[mi], bf[ni], acc[mi][ni]);
        __syncthreads();
    }

    float bvv[4];
    #pragma unroll
    for (int ni = 0; ni < 4; ++ni) bvv[ni] = bo[n0 + wc * 64 + ni * 16 + fr];

    #pragma unroll
    for (int mi = 0; mi < 4; ++mi)
        #pragma unroll
        for (int ni = 0; ni < 4; ++ni) {
            int n = n0 + wc * 64 + ni * 16 + fr;
            #pragma unroll
            for (int i = 0; i < 4; ++i) {
                int m = m0 + wr * 64 + mi * 16 + fg * 4 + i;
                out[(size_t)m * 1024 + n] = acc[mi][ni][i] + bvv[ni];
            }
        }
}

// ---------------------------------------------------------------------------
extern "C" void kernel_launch(void* const* d_in, const int* in_sizes, int n_in,
                              void* d_out, int out_size, void* d_ws, size_t ws_size,
                              hipStream_t stream)
{
    const float* qin = (const float*)d_in[0];
    const float* kin = (const float*)d_in[1];
    const float* vin = (const float*)d_in[2];
    const float* Wq  = (const float*)d_in[3];
    const float* bq  = (const float*)d_in[4];
    const float* Wk  = (const float*)d_in[5];
    const float* bk  = (const float*)d_in[6];
    const float* Wv  = (const float*)d_in[7];
    const float* bv  = (const float*)d_in[8];
    const float* Wo  = (const float*)d_in[9];
    const float* bo  = (const float*)d_in[10];
    float* out = (float*)d_out;

    char* ws = (char*)d_ws;
    unsigned short* Wt  = (unsigned short*)(ws);
    float*          bqs = (float*)(ws + 8388608);
    unsigned short* Qb  = (unsigned short*)(ws + 8392704);
    unsigned short* Kb  = (unsigned short*)(ws + 8392704 + 16777216);
    unsigned short* Vb  = (unsigned short*)(ws + 8392704 + 2 * 16777216);  // [b,h,hd,s]
    unsigned short* Xb  = (unsigned short*)(ws + 8392704 + 3 * 16777216);

    conv_w_kernel<<<dim3(16, 16, 4), 256, 0, stream>>>(Wq, Wk, Wv, Wo, Wt);
    conv_bias_kernel<<<dim3(4), 256, 0, stream>>>(bq, bqs);
    qkv_gemm_kernel<<<dim3(64, 8, 3), 256, 0, stream>>>(qin, kin, vin, Wt, bqs, bk, bv,
                                                        Qb, Kb, Vb);
    attn_kernel<<<dim3(16, 16, 4), 256, 0, stream>>>(Qb, Kb, Vb, Xb);
    out_gemm_kernel<<<dim3(64, 8), 256, 0, stream>>>(Xb, Wt + 3145728, bo, out);
}

// Round 19
// 205.596 us; speedup vs baseline: 1.2128x; 1.2128x over previous
//
#include <hip/hip_runtime.h>
#include <math.h>

constexpr int Bb = 4, Ss = 2048, Dd = 1024, Hh = 16, HDd = 64;

typedef __attribute__((ext_vector_type(8))) short short8;
typedef __attribute__((ext_vector_type(4))) float floatx4;
typedef __attribute__((ext_vector_type(16))) float floatx16;
typedef __attribute__((ext_vector_type(4))) unsigned int uint4v;

__device__ inline unsigned short bf16r(float f) {
    unsigned int u = __builtin_bit_cast(unsigned int, f);
    u += 0x7fffu + ((u >> 16) & 1u);
    return (unsigned short)(u >> 16);
}
// HW packed cvt (RNE, bit-identical to manual round)
__device__ inline unsigned int cvtpk(float lo, float hi) {
    unsigned int r;
    asm("v_cvt_pk_bf16_f32 %0, %1, %2" : "=v"(r) : "v"(lo), "v"(hi));
    return r;
}

__device__ inline void gld16(const void* g, void* l) {
    __builtin_amdgcn_global_load_lds((const __attribute__((address_space(1))) void*)g,
                                     (__attribute__((address_space(3))) void*)l, 16, 0, 0);
}

__device__ inline floatx4 mfma16(short8 a, short8 b, floatx4 c) {
    return __builtin_amdgcn_mfma_f32_16x16x32_bf16(a, b, c, 0, 0, 0);
}
__device__ inline floatx16 mfma32(short8 a, short8 b, floatx16 c) {
    return __builtin_amdgcn_mfma_f32_32x32x16_bf16(a, b, c, 0, 0, 0);
}

// log2(e) folded into Wq/bq so attn can use native exp2 directly.
#define LOG2E 1.4426950408889634f
#define EXP2_SHIFT 17.312340490667562f   // 12 * log2(e)

// ---------------------------------------------------------------------------
// Weight transpose + bf16 convert: Wt[z][n][k] = W_z[k][n] * scale_z
// ---------------------------------------------------------------------------
__global__ __launch_bounds__(256)
void conv_w_kernel(const float* __restrict__ Wq, const float* __restrict__ Wk,
                   const float* __restrict__ Wv, const float* __restrict__ Wo,
                   unsigned short* __restrict__ Wt)
{
    int z = blockIdx.z;
    const float* W = z == 0 ? Wq : z == 1 ? Wk : z == 2 ? Wv : Wo;
    float scale = z == 0 ? 0.125f * LOG2E : 1.0f;
    unsigned short* out = Wt + (size_t)z * 1024 * 1024;

    int r0 = blockIdx.x * 64;
    int c0 = blockIdx.y * 64;
    int t = threadIdx.x;
    int oc = (t & 3) * 16;
    int orow = c0 + (t >> 2);

    float v[16];
    #pragma unroll
    for (int j = 0; j < 16; ++j)
        v[j] = W[(size_t)(r0 + oc + j) * 1024 + orow] * scale;

    unsigned int pk[8];
    #pragma unroll
    for (int j = 0; j < 8; ++j) pk[j] = cvtpk(v[2 * j], v[2 * j + 1]);

    uint4v w0 = {pk[0], pk[1], pk[2], pk[3]};
    uint4v w1 = {pk[4], pk[5], pk[6], pk[7]};
    *(uint4v*)(out + (size_t)orow * 1024 + r0 + oc) = w0;
    *(uint4v*)(out + (size_t)orow * 1024 + r0 + oc + 8) = w1;
}

__global__ __launch_bounds__(256)
void conv_bias_kernel(const float* __restrict__ bq, float* __restrict__ bqs)
{
    int idx = blockIdx.x * 256 + threadIdx.x;
    if (idx < 1024) bqs[idx] = bq[idx] * 0.125f * LOG2E;
}

// ---------------------------------------------------------------------------
// QKV projection GEMM v3 — ALL-ASYNC staging (R15 proven form, 204.8 µs):
//   A staged RAW fp32 via global_load_lds (3-stage, XOR-swizzled via
//   pre-swizzled source), bf16 convert at consume (same cvtpk pairs ->
//   bit-identical results). B (weights) 2-stage gld_lds (L2-hot).
//   Counted fences: issue B(kt+1), A(kt+2); s_waitcnt vmcnt(10); never 0
//   in the loop. lgkmcnt(0)+barrier protects buffer reuse.
//   LDS = 3x16KB (A fp32) + 2x8KB (B) = 64KB.
// ---------------------------------------------------------------------------
__global__ __launch_bounds__(256)
void qkv_gemm_kernel(const float* __restrict__ qin, const float* __restrict__ kin,
                     const float* __restrict__ vin,
                     const unsigned short* __restrict__ Wt,
                     const float* __restrict__ bqs, const float* __restrict__ bk,
                     const float* __restrict__ bv,
                     unsigned short* __restrict__ Qb, unsigned short* __restrict__ Kb,
                     unsigned short* __restrict__ Vb)
{
    int z = blockIdx.z;
    const float* A = z == 0 ? qin : z == 1 ? kin : vin;
    const unsigned short* W = Wt + (size_t)z * 1048576;
    const float* bias = z == 0 ? bqs : z == 1 ? bk : bv;
    unsigned short* O = z == 0 ? Qb : z == 1 ? Kb : Vb;

    __shared__ __align__(16) char qsm[65536];
    char* Aa0 = qsm;                 // A fp32 [128][32], swizzled, 16KB each
    char* Aa1 = qsm + 16384;
    char* Aa2 = qsm + 32768;
    char* Bb0 = qsm + 49152;         // B bf16 [128][32], linear, 8KB each
    char* Bb1 = qsm + 57344;

    int tid = threadIdx.x, lane = tid & 63, w = tid >> 6;
    int wr = w >> 1, wc = w & 1;
    int fr = lane & 15, fg = lane >> 4;
    int m0 = blockIdx.x * 128, n0 = blockIdx.y * 128;

    // A staging geometry: chunk c = w*4+j fills rows w*32+j*8+(lane>>3);
    // source k pre-swizzled so linear DMA lands XOR-swizzled in LDS.
    int arow_base = w * 32 + (lane >> 3);
    int asrc_col = (((lane & 7) ^ ((lane >> 3) & 7)) << 4) >> 2;  // fp32 elems
    const int bRdoB = ((wc * 64 + fr) * 32 + fg * 8) * 2;

    floatx4 acc[4][4] = {};

#define ISSUEA(kt, dst) {                                                       \
    _Pragma("unroll")                                                           \
    for (int j_ = 0; j_ < 4; ++j_) {                                            \
        const float* g_ = A + (size_t)(m0 + arow_base + j_ * 8) * 1024          \
                            + (kt) * 32 + asrc_col;                             \
        gld16(g_, (dst) + (size_t)((w << 8) + (j_ << 6) + lane) * 16);          \
    }}
#define GLB(kt, dst) {                                                          \
    const unsigned short* g0_ = W + (size_t)(n0 + (tid >> 2)) * 1024 + (kt) * 32 + (tid & 3) * 8;          \
    gld16(g0_, (dst) + (size_t)(w * 64) * 16);                                  \
    const unsigned short* g1_ = W + (size_t)(n0 + ((tid + 256) >> 2)) * 1024 + (kt) * 32 + (tid & 3) * 8;  \
    gld16(g1_, (dst) + (size_t)(256 + w * 64) * 16); }
#define COMP(Ac, Bc) { short8 af_[4], bf_[4];                                   \
    _Pragma("unroll")                                                           \
    for (int mi = 0; mi < 4; ++mi) {                                            \
        int row_ = wr * 64 + mi * 16 + fr;                                      \
        int xb_ = (row_ & 7) << 4;                                              \
        floatx4 al_ = *(const floatx4*)((Ac) + row_ * 128 + ((fg * 32) ^ xb_)); \
        floatx4 ah_ = *(const floatx4*)((Ac) + row_ * 128 + ((fg * 32 + 16) ^ xb_)); \
        uint4v u_ = {cvtpk(al_[0], al_[1]), cvtpk(al_[2], al_[3]),              \
                     cvtpk(ah_[0], ah_[1]), cvtpk(ah_[2], ah_[3])};             \
        af_[mi] = __builtin_bit_cast(short8, u_);                               \
    }                                                                           \
    _Pragma("unroll")                                                           \
    for (int ni = 0; ni < 4; ++ni) bf_[ni] = *(const short8*)((Bc) + bRdoB + ni * 1024); \
    _Pragma("unroll")                                                           \
    for (int mi = 0; mi < 4; ++mi)                                              \
        _Pragma("unroll")                                                       \
        for (int ni = 0; ni < 4; ++ni)                                          \
            acc[mi][ni] = mfma16(af_[mi], bf_[ni], acc[mi][ni]); }
#define FV10 { asm volatile("s_waitcnt vmcnt(10)" ::: "memory");                \
    __builtin_amdgcn_s_barrier(); __builtin_amdgcn_sched_barrier(0); }
#define FV6  { asm volatile("s_waitcnt vmcnt(6)" ::: "memory");                 \
    __builtin_amdgcn_s_barrier(); __builtin_amdgcn_sched_barrier(0); }
#define FV0  { asm volatile("s_waitcnt vmcnt(0)" ::: "memory");                 \
    __builtin_amdgcn_s_barrier(); __builtin_amdgcn_sched_barrier(0); }
#define FL   { asm volatile("s_waitcnt lgkmcnt(0)" ::: "memory");               \
    __builtin_amdgcn_s_barrier(); __builtin_amdgcn_sched_barrier(0); }

    // prologue: A(0), B(0), A(1) in flight (10 ops)
    ISSUEA(0, Aa0); GLB(0, Bb0); ISSUEA(1, Aa1);

    // main loop: kt = 0..29, 6-unrolled (A period 3 x B period 2)
    for (int p = 0; p < 5; ++p) {
        int kt = 6 * p;
        GLB(kt + 1, Bb1); ISSUEA(kt + 2, Aa2); FV10; COMP(Aa0, Bb0); FL;   // kt
        GLB(kt + 2, Bb0); ISSUEA(kt + 3, Aa0); FV10; COMP(Aa1, Bb1); FL;   // kt+1
        GLB(kt + 3, Bb1); ISSUEA(kt + 4, Aa1); FV10; COMP(Aa2, Bb0); FL;   // kt+2
        GLB(kt + 4, Bb0); ISSUEA(kt + 5, Aa2); FV10; COMP(Aa0, Bb1); FL;   // kt+3
        GLB(kt + 5, Bb1); ISSUEA(kt + 6, Aa0); FV10; COMP(Aa1, Bb0); FL;   // kt+4
        GLB(kt + 6, Bb0); ISSUEA(kt + 7, Aa1); FV10; COMP(Aa2, Bb1); FL;   // kt+5
    }

    // epilogue: kt = 30 (issue B(31) only), kt = 31
    GLB(31, Bb1);
    FV6; COMP(Aa0, Bb0); FL;
    FV0; COMP(Aa1, Bb1);
    __syncthreads();

#undef ISSUEA
#undef GLB
#undef COMP
#undef FV10
#undef FV6
#undef FV0
#undef FL

    float bvv[4];
    #pragma unroll
    for (int ni = 0; ni < 4; ++ni) bvv[ni] = bias[n0 + wc * 64 + ni * 16 + fr];

    if (z == 2) {
        // Per-wave transpose tile T[64 hd][72 pad] bf16, reusing staging LDS.
        unsigned short* T = (unsigned short*)(qsm) + (size_t)w * 4608;
        #pragma unroll
        for (int mi = 0; mi < 4; ++mi)
            #pragma unroll
            for (int ni = 0; ni < 4; ++ni) {
                int hdl = ni * 16 + fr;
                int sl  = mi * 16 + fg * 4;
                uint2 u2;
                u2.x = cvtpk(acc[mi][ni][0] + bvv[ni], acc[mi][ni][1] + bvv[ni]);
                u2.y = cvtpk(acc[mi][ni][2] + bvv[ni], acc[mi][ni][3] + bvv[ni]);
                *(uint2*)(T + hdl * 72 + sl) = u2;
            }
        __syncthreads();
        int h  = (n0 + wc * 64) >> 6;
        int Ms = m0 + wr * 64;
        int b_ = Ms >> 11, sbase = Ms & 2047;
        unsigned short* Od = O + (((size_t)(b_ * 16 + h) * 64) << 11) + sbase;
        int rg = lane >> 3, sc = lane & 7;
        #pragma unroll
        for (int j = 0; j < 8; ++j) {
            int row = j * 8 + rg;
            uint4v t = *(const uint4v*)(T + row * 72 + sc * 8);
            *(uint4v*)(Od + ((size_t)row << 11) + sc * 8) = t;
        }
    } else {
        #pragma unroll
        for (int mi = 0; mi < 4; ++mi)
            #pragma unroll
            for (int ni = 0; ni < 4; ++ni) {
                int n = n0 + wc * 64 + ni * 16 + fr;
                int h = n >> 6, hd = n & 63;
                #pragma unroll
                for (int i = 0; i < 4; ++i) {
                    int m = m0 + wr * 64 + mi * 16 + fg * 4 + i;
                    int b_ = m >> 11, s = m & 2047;
                    float val = acc[mi][ni][i] + bvv[ni];
                    O[(((size_t)(b_ * 16 + h) * 2048 + s) << 6) + hd] = bf16r(val);
                }
            }
    }
}

// ---------------------------------------------------------------------------
// Flash attention + XCD-chunk remap (R15 proven form)
// ---------------------------------------------------------------------------
__global__ __launch_bounds__(256)
void attn_kernel(const unsigned short* __restrict__ Qb, const unsigned short* __restrict__ Kb,
                 const unsigned short* __restrict__ Vtb, unsigned short* __restrict__ Xb)
{
    __shared__ __align__(16) char smem[32768];

    int pphys = blockIdx.x + (blockIdx.y << 4) + (blockIdx.z << 8);   // 0..1023
    int L = (pphys & 7) * 128 + (pphys >> 3);
    int qt = L & 15;
    int h  = (L >> 4) & 15;
    int b  = L >> 8;

    int tid = threadIdx.x, lane = tid & 63, w = tid >> 6;
    int c = lane & 31, hi = lane >> 5;
    int q0 = qt * 128;
    size_t base = ((size_t)(b * 16 + h)) * 2048 * 64;
    const unsigned short* Qp = Qb + base + (size_t)(q0 + w * 32) * 64;
    const unsigned short* Kp = Kb + base;
    const unsigned short* Vp = Vtb + base;

    short8 qfr[4];
    #pragma unroll
    for (int ks = 0; ks < 4; ++ks)
        qfr[ks] = *(const short8*)(Qp + (size_t)c * 64 + ks * 16 + hi * 8);

    floatx16 acc_o[2] = {};
    floatx16 acc_l = {};
    uint4v onesu = {0x3F803F80u, 0x3F803F80u, 0x3F803F80u, 0x3F803F80u};
    short8 onesb = __builtin_bit_cast(short8, onesu);

    int p0 = tid & 7;
    int r0 = tid >> 3;
    int r1 = r0 + 32;
    int g0 = p0 ^ (r0 & 7);

    auto STAGE = [&](int kt, char* Kd, char* Vd) {
        gld16(Kp + ((size_t)(kt * 64 + r0) << 6) + g0 * 8, Kd + (size_t)tid * 16);
        gld16(Kp + ((size_t)(kt * 64 + r1) << 6) + g0 * 8, Kd + (size_t)(tid + 256) * 16);
        gld16(Vp + ((size_t)r0 << 11) + kt * 64 + g0 * 8, Vd + (size_t)tid * 16);
        gld16(Vp + ((size_t)r1 << 11) + kt * 64 + g0 * 8, Vd + (size_t)(tid + 256) * 16);
    };

    STAGE(0, smem, smem + 8192);
    __syncthreads();

    for (int kt = 0; kt < 32; ++kt) {
        char* Kl = smem + (kt & 1) * 16384;
        char* Vl = Kl + 8192;
        if (kt + 1 < 32) {
            char* Kn = smem + ((kt + 1) & 1) * 16384;
            STAGE(kt + 1, Kn, Kn + 8192);
        }

        #pragma unroll
        for (int kvt = 0; kvt < 2; ++kvt) {
            floatx16 st;
            #pragma unroll
            for (int r = 0; r < 16; ++r) st[r] = -EXP2_SHIFT;

            __builtin_amdgcn_s_setprio(1);
            #pragma unroll
            for (int ks = 0; ks < 4; ++ks) {
                int row = kvt * 32 + c;
                short8 kf = *(const short8*)(Kl + row * 128 +
                                             ((ks * 32 + hi * 16) ^ ((row & 7) << 4)));
                st = mfma32(kf, qfr[ks], st);
            }
            __builtin_amdgcn_s_setprio(0);

            float p[16];
            #pragma unroll
            for (int r = 0; r < 16; ++r)
                p[r] = __builtin_amdgcn_exp2f(st[r]);
            unsigned int j[8];
            #pragma unroll
            for (int t2 = 0; t2 < 8; ++t2)
                j[t2] = cvtpk(p[2 * t2], p[2 * t2 + 1]);
            asm volatile("v_permlane32_swap_b32 %0, %1" : "+v"(j[0]), "+v"(j[2]));
            asm volatile("v_permlane32_swap_b32 %0, %1" : "+v"(j[1]), "+v"(j[3]));
            asm volatile("v_permlane32_swap_b32 %0, %1" : "+v"(j[4]), "+v"(j[6]));
            asm volatile("v_permlane32_swap_b32 %0, %1" : "+v"(j[5]), "+v"(j[7]));
            uint4v pa0 = {j[0], j[1], j[2], j[3]};
            uint4v pa1 = {j[4], j[5], j[6], j[7]};
            short8 paA = __builtin_bit_cast(short8, pa0);
            short8 paB = __builtin_bit_cast(short8, pa1);

            __builtin_amdgcn_s_setprio(1);
            #pragma unroll
            for (int kvs2 = 0; kvs2 < 2; ++kvs2) {
                int kstep = kvt * 2 + kvs2;
                short8 pa = kvs2 ? paB : paA;
                #pragma unroll
                for (int dvt = 0; dvt < 2; ++dvt) {
                    int dv = dvt * 32 + c;
                    short8 vf = *(const short8*)(Vl + dv * 128 +
                                                 ((kstep * 32 + hi * 16) ^ ((dv & 7) << 4)));
                    acc_o[dvt] = mfma32(pa, vf, acc_o[dvt]);
                }
            }
            acc_l = mfma32(paA, onesb, acc_l);
            acc_l = mfma32(paB, onesb, acc_l);
            __builtin_amdgcn_s_setprio(0);
        }
        __syncthreads();
    }

    unsigned short* Ot = (unsigned short*)smem;

    #pragma unroll
    for (int r = 0; r < 16; ++r) {
        int rowq = (r & 3) + 8 * (r >> 2) + 4 * hi;
        float inv = 1.0f / acc_l[r];
        int ql = w * 32 + rowq;
        Ot[ql * 64 + c]      = bf16r(acc_o[0][r] * inv);
        Ot[ql * 64 + 32 + c] = bf16r(acc_o[1][r] * inv);
    }
    __syncthreads();

    {
        int row = tid >> 1, half = tid & 1;
        const unsigned short* src = Ot + row * 64 + half * 32;
        unsigned short* dst = Xb + ((size_t)b * 2048 + q0 + row) * 1024
                                 + h * 64 + half * 32;
        uint4v v0 = *(const uint4v*)(src);
        uint4v v1 = *(const uint4v*)(src + 8);
        uint4v v2 = *(const uint4v*)(src + 16);
        uint4v v3 = *(const uint4v*)(src + 24);
        *(uint4v*)(dst) = v0;
        *(uint4v*)(dst + 8) = v1;
        *(uint4v*)(dst + 16) = v2;
        *(uint4v*)(dst + 24) = v3;
    }
}

// ---------------------------------------------------------------------------
// Output projection GEMM (unchanged)
// ---------------------------------------------------------------------------
__global__ __launch_bounds__(256)
void out_gemm_kernel(const unsigned short* __restrict__ Xb,
                     const unsigned short* __restrict__ Wto,
                     const float* __restrict__ bo, float* __restrict__ out)
{
    __shared__ __align__(16) char osm[32768];
    unsigned short* Asm0 = (unsigned short*)(osm);
    unsigned short* Bsm0 = (unsigned short*)(osm + 8192);
    unsigned short* Asm1 = (unsigned short*)(osm + 16384);
    unsigned short* Bsm1 = (unsigned short*)(osm + 24576);

    int tid = threadIdx.x, lane = tid & 63, w = tid >> 6;
    int wr = w >> 1, wc = w & 1;
    int fr = lane & 15, fg = lane >> 4;
    int m0 = blockIdx.x * 128, n0 = blockIdx.y * 128;

    const int aRdo = (wr * 64 + fr) * 32 + fg * 8;
    const int bRdo = (wc * 64 + fr) * 32 + fg * 8;

    floatx4 acc[4][4] = {};

    auto STAGE = [&](int k0, unsigned short* Ad, unsigned short* Bd) {
        #pragma unroll
        for (int it = 0; it < 2; ++it) {
            int cA = tid + it * 256;
            const unsigned short* ga = Xb + (size_t)(m0 + (cA >> 2)) * 1024 + k0 + (cA & 3) * 8;
            gld16(ga, (char*)Ad + (size_t)(it * 256 + w * 64) * 16);
            const unsigned short* gb = Wto + (size_t)(n0 + (cA >> 2)) * 1024 + k0 + (cA & 3) * 8;
            gld16(gb, (char*)Bd + (size_t)(it * 256 + w * 64) * 16);
        }
    };

    STAGE(0, Asm0, Bsm0);
    __syncthreads();

    for (int kt = 0; kt < 32; ++kt) {
        unsigned short* Acur = (kt & 1) ? Asm1 : Asm0;
        unsigned short* Bcur = (kt & 1) ? Bsm1 : Bsm0;
        if (kt < 31)
            STAGE((kt + 1) * 32, (kt & 1) ? Asm0 : Asm1, (kt & 1) ? Bsm0 : Bsm1);

        short8 af[4], bf[4];
        #pragma unroll
        for (int mi = 0; mi < 4; ++mi) af[mi] = *(const short8*)(Acur + aRdo + mi * 16 * 32);
        #pragma unroll
        for (int ni = 0; ni < 4; ++ni) bf[ni] = *(const short8*)(Bcur + bRdo + ni * 16 * 32);
        #pragma unroll
        for (int mi = 0; mi < 4; ++mi)
            #pragma unroll
            for (int ni = 0; ni < 4; ++ni)
                acc[mi][ni] = mfma16(af[mi], bf[ni], acc[mi][ni]);
        __syncthreads();
    }

    float bvv[4];
    #pragma unroll
    for (int ni = 0; ni < 4; ++ni) bvv[ni] = bo[n0 + wc * 64 + ni * 16 + fr];

    #pragma unroll
    for (int mi = 0; mi < 4; ++mi)
        #pragma unroll
        for (int ni = 0; ni < 4; ++ni) {
            int n = n0 + wc * 64 + ni * 16 + fr;
            #pragma unroll
            for (int i = 0; i < 4; ++i) {
                int m = m0 + wr * 64 + mi * 16 + fg * 4 + i;
                out[(size_t)m * 1024 + n] = acc[mi][ni][i] + bvv[ni];
            }
        }
}

// ---------------------------------------------------------------------------
extern "C" void kernel_launch(void* const* d_in, const int* in_sizes, int n_in,
                              void* d_out, int out_size, void* d_ws, size_t ws_size,
                              hipStream_t stream)
{
    const float* qin = (const float*)d_in[0];
    const float* kin = (const float*)d_in[1];
    const float* vin = (const float*)d_in[2];
    const float* Wq  = (const float*)d_in[3];
    const float* bq  = (const float*)d_in[4];
    const float* Wk  = (const float*)d_in[5];
    const float* bk  = (const float*)d_in[6];
    const float* Wv  = (const float*)d_in[7];
    const float* bv  = (const float*)d_in[8];
    const float* Wo  = (const float*)d_in[9];
    const float* bo  = (const float*)d_in[10];
    float* out = (float*)d_out;

    char* ws = (char*)d_ws;
    unsigned short* Wt  = (unsigned short*)(ws);
    float*          bqs = (float*)(ws + 8388608);
    unsigned short* Qb  = (unsigned short*)(ws + 8392704);
    unsigned short* Kb  = (unsigned short*)(ws + 8392704 + 16777216);
    unsigned short* Vb  = (unsigned short*)(ws + 8392704 + 2 * 16777216);  // [b,h,hd,s]
    unsigned short* Xb  = (unsigned short*)(ws + 8392704 + 3 * 16777216);

    conv_w_kernel<<<dim3(16, 16, 4), 256, 0, stream>>>(Wq, Wk, Wv, Wo, Wt);
    conv_bias_kernel<<<dim3(4), 256, 0, stream>>>(bq, bqs);
    qkv_gemm_kernel<<<dim3(64, 8, 3), 256, 0, stream>>>(qin, kin, vin, Wt, bqs, bk, bv,
                                                        Qb, Kb, Vb);
    attn_kernel<<<dim3(16, 16, 4), 256, 0, stream>>>(Qb, Kb, Vb, Xb);
    out_gemm_kernel<<<dim3(64, 8), 256, 0, stream>>>(Xb, Wt + 3145728, bo, out);
}

// Round 20
// 202.949 us; speedup vs baseline: 1.2286x; 1.0130x over previous
//
#include <hip/hip_runtime.h>
#include <math.h>

constexpr int Bb = 4, Ss = 2048, Dd = 1024, Hh = 16, HDd = 64;

typedef __attribute__((ext_vector_type(8))) short short8;
typedef __attribute__((ext_vector_type(4))) float floatx4;
typedef __attribute__((ext_vector_type(16))) float floatx16;
typedef __attribute__((ext_vector_type(4))) unsigned int uint4v;

__device__ inline unsigned short bf16r(float f) {
    unsigned int u = __builtin_bit_cast(unsigned int, f);
    u += 0x7fffu + ((u >> 16) & 1u);
    return (unsigned short)(u >> 16);
}
// HW packed cvt (RNE, bit-identical to manual round)
__device__ inline unsigned int cvtpk(float lo, float hi) {
    unsigned int r;
    asm("v_cvt_pk_bf16_f32 %0, %1, %2" : "=v"(r) : "v"(lo), "v"(hi));
    return r;
}

__device__ inline void gld16(const void* g, void* l) {
    __builtin_amdgcn_global_load_lds((const __attribute__((address_space(1))) void*)g,
                                     (__attribute__((address_space(3))) void*)l, 16, 0, 0);
}

__device__ inline floatx4 mfma16(short8 a, short8 b, floatx4 c) {
    return __builtin_amdgcn_mfma_f32_16x16x32_bf16(a, b, c, 0, 0, 0);
}
__device__ inline floatx16 mfma32(short8 a, short8 b, floatx16 c) {
    return __builtin_amdgcn_mfma_f32_32x32x16_bf16(a, b, c, 0, 0, 0);
}

// log2(e) folded into Wq/bq so attn can use native exp2 directly.
#define LOG2E 1.4426950408889634f
#define EXP2_SHIFT 17.312340490667562f   // 12 * log2(e)

// ---------------------------------------------------------------------------
// Weight transpose + bf16 convert: Wt[z][n][k] = W_z[k][n] * scale_z
// ---------------------------------------------------------------------------
__global__ __launch_bounds__(256)
void conv_w_kernel(const float* __restrict__ Wq, const float* __restrict__ Wk,
                   const float* __restrict__ Wv, const float* __restrict__ Wo,
                   unsigned short* __restrict__ Wt)
{
    int z = blockIdx.z;
    const float* W = z == 0 ? Wq : z == 1 ? Wk : z == 2 ? Wv : Wo;
    float scale = z == 0 ? 0.125f * LOG2E : 1.0f;
    unsigned short* out = Wt + (size_t)z * 1024 * 1024;

    int r0 = blockIdx.x * 64;
    int c0 = blockIdx.y * 64;
    int t = threadIdx.x;
    int oc = (t & 3) * 16;
    int orow = c0 + (t >> 2);

    float v[16];
    #pragma unroll
    for (int j = 0; j < 16; ++j)
        v[j] = W[(size_t)(r0 + oc + j) * 1024 + orow] * scale;

    unsigned int pk[8];
    #pragma unroll
    for (int j = 0; j < 8; ++j) pk[j] = cvtpk(v[2 * j], v[2 * j + 1]);

    uint4v w0 = {pk[0], pk[1], pk[2], pk[3]};
    uint4v w1 = {pk[4], pk[5], pk[6], pk[7]};
    *(uint4v*)(out + (size_t)orow * 1024 + r0 + oc) = w0;
    *(uint4v*)(out + (size_t)orow * 1024 + r0 + oc + 8) = w1;
}

__global__ __launch_bounds__(256)
void conv_bias_kernel(const float* __restrict__ bq, float* __restrict__ bqs)
{
    int idx = blockIdx.x * 256 + threadIdx.x;
    if (idx < 1024) bqs[idx] = bq[idx] * 0.125f * LOG2E;
}

// ---------------------------------------------------------------------------
// QKV projection GEMM v7 — B-in-LDS, SINGLE barrier per kt:
//   Per iter: FV4(vmcnt(4) lgkmcnt(0); barrier) -> GLB(kt+1) -> ISSUEA(kt+2)
//             -> COMP(kt).
//   Overwrites of Bb[(kt+1)&1] and Aa[(kt+2)%3] both follow the fence that
//   drained their last readers (COMP(kt-1)) via lgkmcnt(0)+barrier -> safe.
//   vmcnt(4): outstanding at fence = A(kt)4 + B(kt)2 (oldest 6, must land)
//   + A(kt+1)4 (kept in flight). A-cover: 2 iterations (same as R15).
//   A: raw fp32 gld_lds, 3 bufs, XOR-swizzled source (R15-verified).
//   B: 2-stage gld_lds (L2-hot weights). LDS = 64KB.
// ---------------------------------------------------------------------------
__global__ __launch_bounds__(256)
void qkv_gemm_kernel(const float* __restrict__ qin, const float* __restrict__ kin,
                     const float* __restrict__ vin,
                     const unsigned short* __restrict__ Wt,
                     const float* __restrict__ bqs, const float* __restrict__ bk,
                     const float* __restrict__ bv,
                     unsigned short* __restrict__ Qb, unsigned short* __restrict__ Kb,
                     unsigned short* __restrict__ Vb)
{
    int z = blockIdx.z;
    const float* A = z == 0 ? qin : z == 1 ? kin : vin;
    const unsigned short* W = Wt + (size_t)z * 1048576;
    const float* bias = z == 0 ? bqs : z == 1 ? bk : bv;
    unsigned short* O = z == 0 ? Qb : z == 1 ? Kb : Vb;

    __shared__ __align__(16) char qsm[65536];
    char* Aa0 = qsm;                 // A fp32 [128][32], swizzled, 16KB each
    char* Aa1 = qsm + 16384;
    char* Aa2 = qsm + 32768;
    char* Bb0 = qsm + 49152;         // B bf16 [128][32], linear, 8KB each
    char* Bb1 = qsm + 57344;

    int tid = threadIdx.x, lane = tid & 63, w = tid >> 6;
    int wr = w >> 1, wc = w & 1;
    int fr = lane & 15, fg = lane >> 4;
    int m0 = blockIdx.x * 128, n0 = blockIdx.y * 128;

    // A staging geometry (R15-verified): chunk j fills rows w*32+j*8+(lane>>3);
    // source k pre-swizzled so linear DMA lands XOR-swizzled in LDS.
    int arow_base = w * 32 + (lane >> 3);
    int asrc_col = (((lane & 7) ^ ((lane >> 3) & 7)) << 4) >> 2;  // fp32 elems
    const int bRdoB = ((wc * 64 + fr) * 32 + fg * 8) * 2;

    floatx4 acc[4][4] = {};

#define ISSUEA(kt, dst) {                                                       \
    _Pragma("unroll")                                                           \
    for (int j_ = 0; j_ < 4; ++j_) {                                            \
        const float* g_ = A + (size_t)(m0 + arow_base + j_ * 8) * 1024          \
                            + (kt) * 32 + asrc_col;                             \
        gld16(g_, (dst) + (size_t)((w << 8) + (j_ << 6) + lane) * 16);          \
    }}
#define GLB(kt, dst) {                                                          \
    const unsigned short* g0_ = W + (size_t)(n0 + (tid >> 2)) * 1024 + (kt) * 32 + (tid & 3) * 8;          \
    gld16(g0_, (dst) + (size_t)(w * 64) * 16);                                  \
    const unsigned short* g1_ = W + (size_t)(n0 + ((tid + 256) >> 2)) * 1024 + (kt) * 32 + (tid & 3) * 8;  \
    gld16(g1_, (dst) + (size_t)(256 + w * 64) * 16); }
#define COMP(Ac, Bc) { short8 af_[4], bf_[4];                                   \
    _Pragma("unroll")                                                           \
    for (int mi = 0; mi < 4; ++mi) {                                            \
        int row_ = wr * 64 + mi * 16 + fr;                                      \
        int xb_ = (row_ & 7) << 4;                                              \
        floatx4 al_ = *(const floatx4*)((Ac) + row_ * 128 + ((fg * 32) ^ xb_)); \
        floatx4 ah_ = *(const floatx4*)((Ac) + row_ * 128 + ((fg * 32 + 16) ^ xb_)); \
        uint4v u_ = {cvtpk(al_[0], al_[1]), cvtpk(al_[2], al_[3]),              \
                     cvtpk(ah_[0], ah_[1]), cvtpk(ah_[2], ah_[3])};             \
        af_[mi] = __builtin_bit_cast(short8, u_);                               \
    }                                                                           \
    _Pragma("unroll")                                                           \
    for (int ni = 0; ni < 4; ++ni) bf_[ni] = *(const short8*)((Bc) + bRdoB + ni * 1024); \
    _Pragma("unroll")                                                           \
    for (int mi = 0; mi < 4; ++mi)                                              \
        _Pragma("unroll")                                                       \
        for (int ni = 0; ni < 4; ++ni)                                          \
            acc[mi][ni] = mfma16(af_[mi], bf_[ni], acc[mi][ni]); }
#define FV4  { asm volatile("s_waitcnt vmcnt(4) lgkmcnt(0)" ::: "memory");      \
    __builtin_amdgcn_s_barrier(); __builtin_amdgcn_sched_barrier(0); }
#define FV0  { asm volatile("s_waitcnt vmcnt(0) lgkmcnt(0)" ::: "memory");      \
    __builtin_amdgcn_s_barrier(); __builtin_amdgcn_sched_barrier(0); }

    // prologue: A(0), B(0), A(1) in flight (A1 issued LAST -> vmcnt(4) works)
    ISSUEA(0, Aa0); GLB(0, Bb0); ISSUEA(1, Aa1);

    // main loop: kt = 0..29, 6-unrolled (A period 3 x B period 2)
    for (int p = 0; p < 5; ++p) {
        int kt = 6 * p;
        FV4; GLB(kt + 1, Bb1); ISSUEA(kt + 2, Aa2); COMP(Aa0, Bb0);   // kt
        FV4; GLB(kt + 2, Bb0); ISSUEA(kt + 3, Aa0); COMP(Aa1, Bb1);   // kt+1
        FV4; GLB(kt + 3, Bb1); ISSUEA(kt + 4, Aa1); COMP(Aa2, Bb0);   // kt+2
        FV4; GLB(kt + 4, Bb0); ISSUEA(kt + 5, Aa2); COMP(Aa0, Bb1);   // kt+3
        FV4; GLB(kt + 5, Bb1); ISSUEA(kt + 6, Aa0); COMP(Aa1, Bb0);   // kt+4
        FV4; GLB(kt + 6, Bb0); ISSUEA(kt + 7, Aa1); COMP(Aa2, Bb1);   // kt+5
    }

    // epilogue: kt = 30 (issue B(31)), kt = 31
    FV4; GLB(31, Bb1); COMP(Aa0, Bb0);
    FV0; COMP(Aa1, Bb1);
    __syncthreads();

#undef ISSUEA
#undef GLB
#undef COMP
#undef FV4
#undef FV0

    float bvv[4];
    #pragma unroll
    for (int ni = 0; ni < 4; ++ni) bvv[ni] = bias[n0 + wc * 64 + ni * 16 + fr];

    if (z == 2) {
        // Per-wave transpose tile T[64 hd][72 pad] bf16, reusing staging LDS.
        unsigned short* T = (unsigned short*)(qsm) + (size_t)w * 4608;
        #pragma unroll
        for (int mi = 0; mi < 4; ++mi)
            #pragma unroll
            for (int ni = 0; ni < 4; ++ni) {
                int hdl = ni * 16 + fr;
                int sl  = mi * 16 + fg * 4;
                uint2 u2;
                u2.x = cvtpk(acc[mi][ni][0] + bvv[ni], acc[mi][ni][1] + bvv[ni]);
                u2.y = cvtpk(acc[mi][ni][2] + bvv[ni], acc[mi][ni][3] + bvv[ni]);
                *(uint2*)(T + hdl * 72 + sl) = u2;
            }
        __syncthreads();
        int h  = (n0 + wc * 64) >> 6;
        int Ms = m0 + wr * 64;
        int b_ = Ms >> 11, sbase = Ms & 2047;
        unsigned short* Od = O + (((size_t)(b_ * 16 + h) * 64) << 11) + sbase;
        int rg = lane >> 3, sc = lane & 7;
        #pragma unroll
        for (int j = 0; j < 8; ++j) {
            int row = j * 8 + rg;
            uint4v t = *(const uint4v*)(T + row * 72 + sc * 8);
            *(uint4v*)(Od + ((size_t)row << 11) + sc * 8) = t;
        }
    } else {
        #pragma unroll
        for (int mi = 0; mi < 4; ++mi)
            #pragma unroll
            for (int ni = 0; ni < 4; ++ni) {
                int n = n0 + wc * 64 + ni * 16 + fr;
                int h = n >> 6, hd = n & 63;
                #pragma unroll
                for (int i = 0; i < 4; ++i) {
                    int m = m0 + wr * 64 + mi * 16 + fg * 4 + i;
                    int b_ = m >> 11, s = m & 2047;
                    float val = acc[mi][ni][i] + bvv[ni];
                    O[(((size_t)(b_ * 16 + h) * 2048 + s) << 6) + hd] = bf16r(val);
                }
            }
    }
}

// ---------------------------------------------------------------------------
// Flash attention + XCD-chunk remap (R15 proven form, unchanged)
// ---------------------------------------------------------------------------
__global__ __launch_bounds__(256)
void attn_kernel(const unsigned short* __restrict__ Qb, const unsigned short* __restrict__ Kb,
                 const unsigned short* __restrict__ Vtb, unsigned short* __restrict__ Xb)
{
    __shared__ __align__(16) char smem[32768];

    int pphys = blockIdx.x + (blockIdx.y << 4) + (blockIdx.z << 8);   // 0..1023
    int L = (pphys & 7) * 128 + (pphys >> 3);
    int qt = L & 15;
    int h  = (L >> 4) & 15;
    int b  = L >> 8;

    int tid = threadIdx.x, lane = tid & 63, w = tid >> 6;
    int c = lane & 31, hi = lane >> 5;
    int q0 = qt * 128;
    size_t base = ((size_t)(b * 16 + h)) * 2048 * 64;
    const unsigned short* Qp = Qb + base + (size_t)(q0 + w * 32) * 64;
    const unsigned short* Kp = Kb + base;
    const unsigned short* Vp = Vtb + base;

    short8 qfr[4];
    #pragma unroll
    for (int ks = 0; ks < 4; ++ks)
        qfr[ks] = *(const short8*)(Qp + (size_t)c * 64 + ks * 16 + hi * 8);

    floatx16 acc_o[2] = {};
    floatx16 acc_l = {};
    uint4v onesu = {0x3F803F80u, 0x3F803F80u, 0x3F803F80u, 0x3F803F80u};
    short8 onesb = __builtin_bit_cast(short8, onesu);

    int p0 = tid & 7;
    int r0 = tid >> 3;
    int r1 = r0 + 32;
    int g0 = p0 ^ (r0 & 7);

    auto STAGE = [&](int kt, char* Kd, char* Vd) {
        gld16(Kp + ((size_t)(kt * 64 + r0) << 6) + g0 * 8, Kd + (size_t)tid * 16);
        gld16(Kp + ((size_t)(kt * 64 + r1) << 6) + g0 * 8, Kd + (size_t)(tid + 256) * 16);
        gld16(Vp + ((size_t)r0 << 11) + kt * 64 + g0 * 8, Vd + (size_t)tid * 16);
        gld16(Vp + ((size_t)r1 << 11) + kt * 64 + g0 * 8, Vd + (size_t)(tid + 256) * 16);
    };

    STAGE(0, smem, smem + 8192);
    __syncthreads();

    for (int kt = 0; kt < 32; ++kt) {
        char* Kl = smem + (kt & 1) * 16384;
        char* Vl = Kl + 8192;
        if (kt + 1 < 32) {
            char* Kn = smem + ((kt + 1) & 1) * 16384;
            STAGE(kt + 1, Kn, Kn + 8192);
        }

        #pragma unroll
        for (int kvt = 0; kvt < 2; ++kvt) {
            floatx16 st;
            #pragma unroll
            for (int r = 0; r < 16; ++r) st[r] = -EXP2_SHIFT;

            __builtin_amdgcn_s_setprio(1);
            #pragma unroll
            for (int ks = 0; ks < 4; ++ks) {
                int row = kvt * 32 + c;
                short8 kf = *(const short8*)(Kl + row * 128 +
                                             ((ks * 32 + hi * 16) ^ ((row & 7) << 4)));
                st = mfma32(kf, qfr[ks], st);
            }
            __builtin_amdgcn_s_setprio(0);

            float p[16];
            #pragma unroll
            for (int r = 0; r < 16; ++r)
                p[r] = __builtin_amdgcn_exp2f(st[r]);
            unsigned int j[8];
            #pragma unroll
            for (int t2 = 0; t2 < 8; ++t2)
                j[t2] = cvtpk(p[2 * t2], p[2 * t2 + 1]);
            asm volatile("v_permlane32_swap_b32 %0, %1" : "+v"(j[0]), "+v"(j[2]));
            asm volatile("v_permlane32_swap_b32 %0, %1" : "+v"(j[1]), "+v"(j[3]));
            asm volatile("v_permlane32_swap_b32 %0, %1" : "+v"(j[4]), "+v"(j[6]));
            asm volatile("v_permlane32_swap_b32 %0, %1" : "+v"(j[5]), "+v"(j[7]));
            uint4v pa0 = {j[0], j[1], j[2], j[3]};
            uint4v pa1 = {j[4], j[5], j[6], j[7]};
            short8 paA = __builtin_bit_cast(short8, pa0);
            short8 paB = __builtin_bit_cast(short8, pa1);

            __builtin_amdgcn_s_setprio(1);
            #pragma unroll
            for (int kvs2 = 0; kvs2 < 2; ++kvs2) {
                int kstep = kvt * 2 + kvs2;
                short8 pa = kvs2 ? paB : paA;
                #pragma unroll
                for (int dvt = 0; dvt < 2; ++dvt) {
                    int dv = dvt * 32 + c;
                    short8 vf = *(const short8*)(Vl + dv * 128 +
                                                 ((kstep * 32 + hi * 16) ^ ((dv & 7) << 4)));
                    acc_o[dvt] = mfma32(pa, vf, acc_o[dvt]);
                }
            }
            acc_l = mfma32(paA, onesb, acc_l);
            acc_l = mfma32(paB, onesb, acc_l);
            __builtin_amdgcn_s_setprio(0);
        }
        __syncthreads();
    }

    unsigned short* Ot = (unsigned short*)smem;

    #pragma unroll
    for (int r = 0; r < 16; ++r) {
        int rowq = (r & 3) + 8 * (r >> 2) + 4 * hi;
        float inv = 1.0f / acc_l[r];
        int ql = w * 32 + rowq;
        Ot[ql * 64 + c]      = bf16r(acc_o[0][r] * inv);
        Ot[ql * 64 + 32 + c] = bf16r(acc_o[1][r] * inv);
    }
    __syncthreads();

    {
        int row = tid >> 1, half = tid & 1;
        const unsigned short* src = Ot + row * 64 + half * 32;
        unsigned short* dst = Xb + ((size_t)b * 2048 + q0 + row) * 1024
                                 + h * 64 + half * 32;
        uint4v v0 = *(const uint4v*)(src);
        uint4v v1 = *(const uint4v*)(src + 8);
        uint4v v2 = *(const uint4v*)(src + 16);
        uint4v v3 = *(const uint4v*)(src + 24);
        *(uint4v*)(dst) = v0;
        *(uint4v*)(dst + 8) = v1;
        *(uint4v*)(dst + 16) = v2;
        *(uint4v*)(dst + 24) = v3;
    }
}

// ---------------------------------------------------------------------------
// Output projection GEMM (unchanged)
// ---------------------------------------------------------------------------
__global__ __launch_bounds__(256)
void out_gemm_kernel(const unsigned short* __restrict__ Xb,
                     const unsigned short* __restrict__ Wto,
                     const float* __restrict__ bo, float* __restrict__ out)
{
    __shared__ __align__(16) char osm[32768];
    unsigned short* Asm0 = (unsigned short*)(osm);
    unsigned short* Bsm0 = (unsigned short*)(osm + 8192);
    unsigned short* Asm1 = (unsigned short*)(osm + 16384);
    unsigned short* Bsm1 = (unsigned short*)(osm + 24576);

    int tid = threadIdx.x, lane = tid & 63, w = tid >> 6;
    int wr = w >> 1, wc = w & 1;
    int fr = lane & 15, fg = lane >> 4;
    int m0 = blockIdx.x * 128, n0 = blockIdx.y * 128;

    const int aRdo = (wr * 64 + fr) * 32 + fg * 8;
    const int bRdo = (wc * 64 + fr) * 32 + fg * 8;

    floatx4 acc[4][4] = {};

    auto STAGE = [&](int k0, unsigned short* Ad, unsigned short* Bd) {
        #pragma unroll
        for (int it = 0; it < 2; ++it) {
            int cA = tid + it * 256;
            const unsigned short* ga = Xb + (size_t)(m0 + (cA >> 2)) * 1024 + k0 + (cA & 3) * 8;
            gld16(ga, (char*)Ad + (size_t)(it * 256 + w * 64) * 16);
            const unsigned short* gb = Wto + (size_t)(n0 + (cA >> 2)) * 1024 + k0 + (cA & 3) * 8;
            gld16(gb, (char*)Bd + (size_t)(it * 256 + w * 64) * 16);
        }
    };

    STAGE(0, Asm0, Bsm0);
    __syncthreads();

    for (int kt = 0; kt < 32; ++kt) {
        unsigned short* Acur = (kt & 1) ? Asm1 : Asm0;
        unsigned short* Bcur = (kt & 1) ? Bsm1 : Bsm0;
        if (kt < 31)
            STAGE((kt + 1) * 32, (kt & 1) ? Asm0 : Asm1, (kt & 1) ? Bsm0 : Bsm1);

        short8 af[4], bf[4];
        #pragma unroll
        for (int mi = 0; mi < 4; ++mi) af[mi] = *(const short8*)(Acur + aRdo + mi * 16 * 32);
        #pragma unroll
        for (int ni = 0; ni < 4; ++ni) bf[ni] = *(const short8*)(Bcur + bRdo + ni * 16 * 32);
        #pragma unroll
        for (int mi = 0; mi < 4; ++mi)
            #pragma unroll
            for (int ni = 0; ni < 4; ++ni)
                acc[mi][ni] = mfma16(af[mi], bf[ni], acc[mi][ni]);
        __syncthreads();
    }

    float bvv[4];
    #pragma unroll
    for (int ni = 0; ni < 4; ++ni) bvv[ni] = bo[n0 + wc * 64 + ni * 16 + fr];

    #pragma unroll
    for (int mi = 0; mi < 4; ++mi)
        #pragma unroll
        for (int ni = 0; ni < 4; ++ni) {
            int n = n0 + wc * 64 + ni * 16 + fr;
            #pragma unroll
            for (int i = 0; i < 4; ++i) {
                int m = m0 + wr * 64 + mi * 16 + fg * 4 + i;
                out[(size_t)m * 1024 + n] = acc[mi][ni][i] + bvv[ni];
            }
        }
}

// ---------------------------------------------------------------------------
extern "C" void kernel_launch(void* const* d_in, const int* in_sizes, int n_in,
                              void* d_out, int out_size, void* d_ws, size_t ws_size,
                              hipStream_t stream)
{
    const float* qin = (const float*)d_in[0];
    const float* kin = (const float*)d_in[1];
    const float* vin = (const float*)d_in[2];
    const float* Wq  = (const float*)d_in[3];
    const float* bq  = (const float*)d_in[4];
    const float* Wk  = (const float*)d_in[5];
    const float* bk  = (const float*)d_in[6];
    const float* Wv  = (const float*)d_in[7];
    const float* bv  = (const float*)d_in[8];
    const float* Wo  = (const float*)d_in[9];
    const float* bo  = (const float*)d_in[10];
    float* out = (float*)d_out;

    char* ws = (char*)d_ws;
    unsigned short* Wt  = (unsigned short*)(ws);
    float*          bqs = (float*)(ws + 8388608);
    unsigned short* Qb  = (unsigned short*)(ws + 8392704);
    unsigned short* Kb  = (unsigned short*)(ws + 8392704 + 16777216);
    unsigned short* Vb  = (unsigned short*)(ws + 8392704 + 2 * 16777216);  // [b,h,hd,s]
    unsigned short* Xb  = (unsigned short*)(ws + 8392704 + 3 * 16777216);

    conv_w_kernel<<<dim3(16, 16, 4), 256, 0, stream>>>(Wq, Wk, Wv, Wo, Wt);
    conv_bias_kernel<<<dim3(4), 256, 0, stream>>>(bq, bqs);
    qkv_gemm_kernel<<<dim3(64, 8, 3), 256, 0, stream>>>(qin, kin, vin, Wt, bqs, bk, bv,
                                                        Qb, Kb, Vb);
    attn_kernel<<<dim3(16, 16, 4), 256, 0, stream>>>(Qb, Kb, Vb, Xb);
    out_gemm_kernel<<<dim3(64, 8), 256, 0, stream>>>(Xb, Wt + 3145728, bo, out);
}

// Round 21
// 201.663 us; speedup vs baseline: 1.2364x; 1.0064x over previous
//
#include <hip/hip_runtime.h>
#include <math.h>

constexpr int Bb = 4, Ss = 2048, Dd = 1024, Hh = 16, HDd = 64;

typedef __attribute__((ext_vector_type(8))) short short8;
typedef __attribute__((ext_vector_type(4))) float floatx4;
typedef __attribute__((ext_vector_type(16))) float floatx16;
typedef __attribute__((ext_vector_type(4))) unsigned int uint4v;

__device__ inline unsigned short bf16r(float f) {
    unsigned int u = __builtin_bit_cast(unsigned int, f);
    u += 0x7fffu + ((u >> 16) & 1u);
    return (unsigned short)(u >> 16);
}
// HW packed cvt (RNE, bit-identical to manual round)
__device__ inline unsigned int cvtpk(float lo, float hi) {
    unsigned int r;
    asm("v_cvt_pk_bf16_f32 %0, %1, %2" : "=v"(r) : "v"(lo), "v"(hi));
    return r;
}

__device__ inline void gld16(const void* g, void* l) {
    __builtin_amdgcn_global_load_lds((const __attribute__((address_space(1))) void*)g,
                                     (__attribute__((address_space(3))) void*)l, 16, 0, 0);
}

__device__ inline floatx4 mfma16(short8 a, short8 b, floatx4 c) {
    return __builtin_amdgcn_mfma_f32_16x16x32_bf16(a, b, c, 0, 0, 0);
}
__device__ inline floatx16 mfma32(short8 a, short8 b, floatx16 c) {
    return __builtin_amdgcn_mfma_f32_32x32x16_bf16(a, b, c, 0, 0, 0);
}

// log2(e) folded into Wq/bq so attn can use native exp2 directly.
#define LOG2E 1.4426950408889634f
#define EXP2_SHIFT 17.312340490667562f   // 12 * log2(e)

// ---------------------------------------------------------------------------
// Weight transpose + bf16 convert: Wt[z][n][k] = W_z[k][n] * scale_z.
// Block (0,0,z=0) additionally converts the q-bias (saves a launch).
// ---------------------------------------------------------------------------
__global__ __launch_bounds__(256)
void conv_w_kernel(const float* __restrict__ Wq, const float* __restrict__ Wk,
                   const float* __restrict__ Wv, const float* __restrict__ Wo,
                   const float* __restrict__ bq, float* __restrict__ bqs,
                   unsigned short* __restrict__ Wt)
{
    int z = blockIdx.z;
    const float* W = z == 0 ? Wq : z == 1 ? Wk : z == 2 ? Wv : Wo;
    float scale = z == 0 ? 0.125f * LOG2E : 1.0f;
    unsigned short* out = Wt + (size_t)z * 1024 * 1024;

    int r0 = blockIdx.x * 64;
    int c0 = blockIdx.y * 64;
    int t = threadIdx.x;
    int oc = (t & 3) * 16;
    int orow = c0 + (t >> 2);

    // fold conv_bias: one block handles the 1024-elem q-bias scale
    if (z == 0 && blockIdx.x == 0 && blockIdx.y == 0) {
        #pragma unroll
        for (int jj = 0; jj < 4; ++jj)
            bqs[t + jj * 256] = bq[t + jj * 256] * 0.125f * LOG2E;
    }

    float v[16];
    #pragma unroll
    for (int j = 0; j < 16; ++j)
        v[j] = W[(size_t)(r0 + oc + j) * 1024 + orow] * scale;

    unsigned int pk[8];
    #pragma unroll
    for (int j = 0; j < 8; ++j) pk[j] = cvtpk(v[2 * j], v[2 * j + 1]);

    uint4v w0 = {pk[0], pk[1], pk[2], pk[3]};
    uint4v w1 = {pk[4], pk[5], pk[6], pk[7]};
    *(uint4v*)(out + (size_t)orow * 1024 + r0 + oc) = w0;
    *(uint4v*)(out + (size_t)orow * 1024 + r0 + oc + 8) = w1;
}

// ---------------------------------------------------------------------------
// QKV projection GEMM v7 — B-in-LDS, SINGLE barrier per kt (verified 202.9):
//   Per iter: FV4(vmcnt(4) lgkmcnt(0); barrier) -> GLB(kt+1) -> ISSUEA(kt+2)
//             -> COMP(kt). Overwrites follow the fence that drained their
//   last readers via lgkmcnt(0)+barrier -> race-free.
//   vmcnt(4): outstanding at fence = A(kt)4 + B(kt)2 (must land) + A(kt+1)4.
//   A: raw fp32 gld_lds, 3 bufs, XOR-swizzled source. B: 2-stage gld_lds.
// ---------------------------------------------------------------------------
__global__ __launch_bounds__(256)
void qkv_gemm_kernel(const float* __restrict__ qin, const float* __restrict__ kin,
                     const float* __restrict__ vin,
                     const unsigned short* __restrict__ Wt,
                     const float* __restrict__ bqs, const float* __restrict__ bk,
                     const float* __restrict__ bv,
                     unsigned short* __restrict__ Qb, unsigned short* __restrict__ Kb,
                     unsigned short* __restrict__ Vb)
{
    int z = blockIdx.z;
    const float* A = z == 0 ? qin : z == 1 ? kin : vin;
    const unsigned short* W = Wt + (size_t)z * 1048576;
    const float* bias = z == 0 ? bqs : z == 1 ? bk : bv;
    unsigned short* O = z == 0 ? Qb : z == 1 ? Kb : Vb;

    __shared__ __align__(16) char qsm[65536];
    char* Aa0 = qsm;                 // A fp32 [128][32], swizzled, 16KB each
    char* Aa1 = qsm + 16384;
    char* Aa2 = qsm + 32768;
    char* Bb0 = qsm + 49152;         // B bf16 [128][32], linear, 8KB each
    char* Bb1 = qsm + 57344;

    int tid = threadIdx.x, lane = tid & 63, w = tid >> 6;
    int wr = w >> 1, wc = w & 1;
    int fr = lane & 15, fg = lane >> 4;
    int m0 = blockIdx.x * 128, n0 = blockIdx.y * 128;

    int arow_base = w * 32 + (lane >> 3);
    int asrc_col = (((lane & 7) ^ ((lane >> 3) & 7)) << 4) >> 2;  // fp32 elems
    const int bRdoB = ((wc * 64 + fr) * 32 + fg * 8) * 2;

    floatx4 acc[4][4] = {};

#define ISSUEA(kt, dst) {                                                       \
    _Pragma("unroll")                                                           \
    for (int j_ = 0; j_ < 4; ++j_) {                                            \
        const float* g_ = A + (size_t)(m0 + arow_base + j_ * 8) * 1024          \
                            + (kt) * 32 + asrc_col;                             \
        gld16(g_, (dst) + (size_t)((w << 8) + (j_ << 6) + lane) * 16);          \
    }}
#define GLB(kt, dst) {                                                          \
    const unsigned short* g0_ = W + (size_t)(n0 + (tid >> 2)) * 1024 + (kt) * 32 + (tid & 3) * 8;          \
    gld16(g0_, (dst) + (size_t)(w * 64) * 16);                                  \
    const unsigned short* g1_ = W + (size_t)(n0 + ((tid + 256) >> 2)) * 1024 + (kt) * 32 + (tid & 3) * 8;  \
    gld16(g1_, (dst) + (size_t)(256 + w * 64) * 16); }
#define COMP(Ac, Bc) { short8 af_[4], bf_[4];                                   \
    _Pragma("unroll")                                                           \
    for (int mi = 0; mi < 4; ++mi) {                                            \
        int row_ = wr * 64 + mi * 16 + fr;                                      \
        int xb_ = (row_ & 7) << 4;                                              \
        floatx4 al_ = *(const floatx4*)((Ac) + row_ * 128 + ((fg * 32) ^ xb_)); \
        floatx4 ah_ = *(const floatx4*)((Ac) + row_ * 128 + ((fg * 32 + 16) ^ xb_)); \
        uint4v u_ = {cvtpk(al_[0], al_[1]), cvtpk(al_[2], al_[3]),              \
                     cvtpk(ah_[0], ah_[1]), cvtpk(ah_[2], ah_[3])};             \
        af_[mi] = __builtin_bit_cast(short8, u_);                               \
    }                                                                           \
    _Pragma("unroll")                                                           \
    for (int ni = 0; ni < 4; ++ni) bf_[ni] = *(const short8*)((Bc) + bRdoB + ni * 1024); \
    _Pragma("unroll")                                                           \
    for (int mi = 0; mi < 4; ++mi)                                              \
        _Pragma("unroll")                                                       \
        for (int ni = 0; ni < 4; ++ni)                                          \
            acc[mi][ni] = mfma16(af_[mi], bf_[ni], acc[mi][ni]); }
#define FV4  { asm volatile("s_waitcnt vmcnt(4) lgkmcnt(0)" ::: "memory");      \
    __builtin_amdgcn_s_barrier(); __builtin_amdgcn_sched_barrier(0); }
#define FV0  { asm volatile("s_waitcnt vmcnt(0) lgkmcnt(0)" ::: "memory");      \
    __builtin_amdgcn_s_barrier(); __builtin_amdgcn_sched_barrier(0); }

    // prologue: A(0), B(0), A(1) in flight (A1 issued LAST -> vmcnt(4) works)
    ISSUEA(0, Aa0); GLB(0, Bb0); ISSUEA(1, Aa1);

    // main loop: kt = 0..29, 6-unrolled (A period 3 x B period 2)
    for (int p = 0; p < 5; ++p) {
        int kt = 6 * p;
        FV4; GLB(kt + 1, Bb1); ISSUEA(kt + 2, Aa2); COMP(Aa0, Bb0);   // kt
        FV4; GLB(kt + 2, Bb0); ISSUEA(kt + 3, Aa0); COMP(Aa1, Bb1);   // kt+1
        FV4; GLB(kt + 3, Bb1); ISSUEA(kt + 4, Aa1); COMP(Aa2, Bb0);   // kt+2
        FV4; GLB(kt + 4, Bb0); ISSUEA(kt + 5, Aa2); COMP(Aa0, Bb1);   // kt+3
        FV4; GLB(kt + 5, Bb1); ISSUEA(kt + 6, Aa0); COMP(Aa1, Bb0);   // kt+4
        FV4; GLB(kt + 6, Bb0); ISSUEA(kt + 7, Aa1); COMP(Aa2, Bb1);   // kt+5
    }

    // epilogue: kt = 30 (issue B(31)), kt = 31
    FV4; GLB(31, Bb1); COMP(Aa0, Bb0);
    FV0; COMP(Aa1, Bb1);
    __syncthreads();

#undef ISSUEA
#undef GLB
#undef COMP
#undef FV4
#undef FV0

    float bvv[4];
    #pragma unroll
    for (int ni = 0; ni < 4; ++ni) bvv[ni] = bias[n0 + wc * 64 + ni * 16 + fr];

    if (z == 2) {
        // Per-wave transpose tile T[64 hd][72 pad] bf16, reusing staging LDS.
        unsigned short* T = (unsigned short*)(qsm) + (size_t)w * 4608;
        #pragma unroll
        for (int mi = 0; mi < 4; ++mi)
            #pragma unroll
            for (int ni = 0; ni < 4; ++ni) {
                int hdl = ni * 16 + fr;
                int sl  = mi * 16 + fg * 4;
                uint2 u2;
                u2.x = cvtpk(acc[mi][ni][0] + bvv[ni], acc[mi][ni][1] + bvv[ni]);
                u2.y = cvtpk(acc[mi][ni][2] + bvv[ni], acc[mi][ni][3] + bvv[ni]);
                *(uint2*)(T + hdl * 72 + sl) = u2;
            }
        __syncthreads();
        int h  = (n0 + wc * 64) >> 6;
        int Ms = m0 + wr * 64;
        int b_ = Ms >> 11, sbase = Ms & 2047;
        unsigned short* Od = O + (((size_t)(b_ * 16 + h) * 64) << 11) + sbase;
        int rg = lane >> 3, sc = lane & 7;
        #pragma unroll
        for (int j = 0; j < 8; ++j) {
            int row = j * 8 + rg;
            uint4v t = *(const uint4v*)(T + row * 72 + sc * 8);
            *(uint4v*)(Od + ((size_t)row << 11) + sc * 8) = t;
        }
    } else {
        #pragma unroll
        for (int mi = 0; mi < 4; ++mi)
            #pragma unroll
            for (int ni = 0; ni < 4; ++ni) {
                int n = n0 + wc * 64 + ni * 16 + fr;
                int h = n >> 6, hd = n & 63;
                #pragma unroll
                for (int i = 0; i < 4; ++i) {
                    int m = m0 + wr * 64 + mi * 16 + fg * 4 + i;
                    int b_ = m >> 11, s = m & 2047;
                    float val = acc[mi][ni][i] + bvv[ni];
                    O[(((size_t)(b_ * 16 + h) * 2048 + s) << 6) + hd] = bf16r(val);
                }
            }
    }
}

// ---------------------------------------------------------------------------
// Flash attention + XCD-chunk remap (verified form, unchanged)
// ---------------------------------------------------------------------------
__global__ __launch_bounds__(256)
void attn_kernel(const unsigned short* __restrict__ Qb, const unsigned short* __restrict__ Kb,
                 const unsigned short* __restrict__ Vtb, unsigned short* __restrict__ Xb)
{
    __shared__ __align__(16) char smem[32768];

    int pphys = blockIdx.x + (blockIdx.y << 4) + (blockIdx.z << 8);   // 0..1023
    int L = (pphys & 7) * 128 + (pphys >> 3);
    int qt = L & 15;
    int h  = (L >> 4) & 15;
    int b  = L >> 8;

    int tid = threadIdx.x, lane = tid & 63, w = tid >> 6;
    int c = lane & 31, hi = lane >> 5;
    int q0 = qt * 128;
    size_t base = ((size_t)(b * 16 + h)) * 2048 * 64;
    const unsigned short* Qp = Qb + base + (size_t)(q0 + w * 32) * 64;
    const unsigned short* Kp = Kb + base;
    const unsigned short* Vp = Vtb + base;

    short8 qfr[4];
    #pragma unroll
    for (int ks = 0; ks < 4; ++ks)
        qfr[ks] = *(const short8*)(Qp + (size_t)c * 64 + ks * 16 + hi * 8);

    floatx16 acc_o[2] = {};
    floatx16 acc_l = {};
    uint4v onesu = {0x3F803F80u, 0x3F803F80u, 0x3F803F80u, 0x3F803F80u};
    short8 onesb = __builtin_bit_cast(short8, onesu);

    int p0 = tid & 7;
    int r0 = tid >> 3;
    int r1 = r0 + 32;
    int g0 = p0 ^ (r0 & 7);

    auto STAGE = [&](int kt, char* Kd, char* Vd) {
        gld16(Kp + ((size_t)(kt * 64 + r0) << 6) + g0 * 8, Kd + (size_t)tid * 16);
        gld16(Kp + ((size_t)(kt * 64 + r1) << 6) + g0 * 8, Kd + (size_t)(tid + 256) * 16);
        gld16(Vp + ((size_t)r0 << 11) + kt * 64 + g0 * 8, Vd + (size_t)tid * 16);
        gld16(Vp + ((size_t)r1 << 11) + kt * 64 + g0 * 8, Vd + (size_t)(tid + 256) * 16);
    };

    STAGE(0, smem, smem + 8192);
    __syncthreads();

    for (int kt = 0; kt < 32; ++kt) {
        char* Kl = smem + (kt & 1) * 16384;
        char* Vl = Kl + 8192;
        if (kt + 1 < 32) {
            char* Kn = smem + ((kt + 1) & 1) * 16384;
            STAGE(kt + 1, Kn, Kn + 8192);
        }

        #pragma unroll
        for (int kvt = 0; kvt < 2; ++kvt) {
            floatx16 st;
            #pragma unroll
            for (int r = 0; r < 16; ++r) st[r] = -EXP2_SHIFT;

            __builtin_amdgcn_s_setprio(1);
            #pragma unroll
            for (int ks = 0; ks < 4; ++ks) {
                int row = kvt * 32 + c;
                short8 kf = *(const short8*)(Kl + row * 128 +
                                             ((ks * 32 + hi * 16) ^ ((row & 7) << 4)));
                st = mfma32(kf, qfr[ks], st);
            }
            __builtin_amdgcn_s_setprio(0);

            float p[16];
            #pragma unroll
            for (int r = 0; r < 16; ++r)
                p[r] = __builtin_amdgcn_exp2f(st[r]);
            unsigned int j[8];
            #pragma unroll
            for (int t2 = 0; t2 < 8; ++t2)
                j[t2] = cvtpk(p[2 * t2], p[2 * t2 + 1]);
            asm volatile("v_permlane32_swap_b32 %0, %1" : "+v"(j[0]), "+v"(j[2]));
            asm volatile("v_permlane32_swap_b32 %0, %1" : "+v"(j[1]), "+v"(j[3]));
            asm volatile("v_permlane32_swap_b32 %0, %1" : "+v"(j[4]), "+v"(j[6]));
            asm volatile("v_permlane32_swap_b32 %0, %1" : "+v"(j[5]), "+v"(j[7]));
            uint4v pa0 = {j[0], j[1], j[2], j[3]};
            uint4v pa1 = {j[4], j[5], j[6], j[7]};
            short8 paA = __builtin_bit_cast(short8, pa0);
            short8 paB = __builtin_bit_cast(short8, pa1);

            __builtin_amdgcn_s_setprio(1);
            #pragma unroll
            for (int kvs2 = 0; kvs2 < 2; ++kvs2) {
                int kstep = kvt * 2 + kvs2;
                short8 pa = kvs2 ? paB : paA;
                #pragma unroll
                for (int dvt = 0; dvt < 2; ++dvt) {
                    int dv = dvt * 32 + c;
                    short8 vf = *(const short8*)(Vl + dv * 128 +
                                                 ((kstep * 32 + hi * 16) ^ ((dv & 7) << 4)));
                    acc_o[dvt] = mfma32(pa, vf, acc_o[dvt]);
                }
            }
            acc_l = mfma32(paA, onesb, acc_l);
            acc_l = mfma32(paB, onesb, acc_l);
            __builtin_amdgcn_s_setprio(0);
        }
        __syncthreads();
    }

    unsigned short* Ot = (unsigned short*)smem;

    #pragma unroll
    for (int r = 0; r < 16; ++r) {
        int rowq = (r & 3) + 8 * (r >> 2) + 4 * hi;
        float inv = 1.0f / acc_l[r];
        int ql = w * 32 + rowq;
        Ot[ql * 64 + c]      = bf16r(acc_o[0][r] * inv);
        Ot[ql * 64 + 32 + c] = bf16r(acc_o[1][r] * inv);
    }
    __syncthreads();

    {
        int row = tid >> 1, half = tid & 1;
        const unsigned short* src = Ot + row * 64 + half * 32;
        unsigned short* dst = Xb + ((size_t)b * 2048 + q0 + row) * 1024
                                 + h * 64 + half * 32;
        uint4v v0 = *(const uint4v*)(src);
        uint4v v1 = *(const uint4v*)(src + 8);
        uint4v v2 = *(const uint4v*)(src + 16);
        uint4v v3 = *(const uint4v*)(src + 24);
        *(uint4v*)(dst) = v0;
        *(uint4v*)(dst + 8) = v1;
        *(uint4v*)(dst + 16) = v2;
        *(uint4v*)(dst + 24) = v3;
    }
}

// ---------------------------------------------------------------------------
// Output projection GEMM (unchanged)
// ---------------------------------------------------------------------------
__global__ __launch_bounds__(256)
void out_gemm_kernel(const unsigned short* __restrict__ Xb,
                     const unsigned short* __restrict__ Wto,
                     const float* __restrict__ bo, float* __restrict__ out)
{
    __shared__ __align__(16) char osm[32768];
    unsigned short* Asm0 = (unsigned short*)(osm);
    unsigned short* Bsm0 = (unsigned short*)(osm + 8192);
    unsigned short* Asm1 = (unsigned short*)(osm + 16384);
    unsigned short* Bsm1 = (unsigned short*)(osm + 24576);

    int tid = threadIdx.x, lane = tid & 63, w = tid >> 6;
    int wr = w >> 1, wc = w & 1;
    int fr = lane & 15, fg = lane >> 4;
    int m0 = blockIdx.x * 128, n0 = blockIdx.y * 128;

    const int aRdo = (wr * 64 + fr) * 32 + fg * 8;
    const int bRdo = (wc * 64 + fr) * 32 + fg * 8;

    floatx4 acc[4][4] = {};

    auto STAGE = [&](int k0, unsigned short* Ad, unsigned short* Bd) {
        #pragma unroll
        for (int it = 0; it < 2; ++it) {
            int cA = tid + it * 256;
            const unsigned short* ga = Xb + (size_t)(m0 + (cA >> 2)) * 1024 + k0 + (cA & 3) * 8;
            gld16(ga, (char*)Ad + (size_t)(it * 256 + w * 64) * 16);
            const unsigned short* gb = Wto + (size_t)(n0 + (cA >> 2)) * 1024 + k0 + (cA & 3) * 8;
            gld16(gb, (char*)Bd + (size_t)(it * 256 + w * 64) * 16);
        }
    };

    STAGE(0, Asm0, Bsm0);
    __syncthreads();

    for (int kt = 0; kt < 32; ++kt) {
        unsigned short* Acur = (kt & 1) ? Asm1 : Asm0;
        unsigned short* Bcur = (kt & 1) ? Bsm1 : Bsm0;
        if (kt < 31)
            STAGE((kt + 1) * 32, (kt & 1) ? Asm0 : Asm1, (kt & 1) ? Bsm0 : Bsm1);

        short8 af[4], bf[4];
        #pragma unroll
        for (int mi = 0; mi < 4; ++mi) af[mi] = *(const short8*)(Acur + aRdo + mi * 16 * 32);
        #pragma unroll
        for (int ni = 0; ni < 4; ++ni) bf[ni] = *(const short8*)(Bcur + bRdo + ni * 16 * 32);
        #pragma unroll
        for (int mi = 0; mi < 4; ++mi)
            #pragma unroll
            for (int ni = 0; ni < 4; ++ni)
                acc[mi][ni] = mfma16(af[mi], bf[ni], acc[mi][ni]);
        __syncthreads();
    }

    float bvv[4];
    #pragma unroll
    for (int ni = 0; ni < 4; ++ni) bvv[ni] = bo[n0 + wc * 64 + ni * 16 + fr];

    #pragma unroll
    for (int mi = 0; mi < 4; ++mi)
        #pragma unroll
        for (int ni = 0; ni < 4; ++ni) {
            int n = n0 + wc * 64 + ni * 16 + fr;
            #pragma unroll
            for (int i = 0; i < 4; ++i) {
                int m = m0 + wr * 64 + mi * 16 + fg * 4 + i;
                out[(size_t)m * 1024 + n] = acc[mi][ni][i] + bvv[ni];
            }
        }
}

// ---------------------------------------------------------------------------
extern "C" void kernel_launch(void* const* d_in, const int* in_sizes, int n_in,
                              void* d_out, int out_size, void* d_ws, size_t ws_size,
                              hipStream_t stream)
{
    const float* qin = (const float*)d_in[0];
    const float* kin = (const float*)d_in[1];
    const float* vin = (const float*)d_in[2];
    const float* Wq  = (const float*)d_in[3];
    const float* bq  = (const float*)d_in[4];
    const float* Wk  = (const float*)d_in[5];
    const float* bk  = (const float*)d_in[6];
    const float* Wv  = (const float*)d_in[7];
    const float* bv  = (const float*)d_in[8];
    const float* Wo  = (const float*)d_in[9];
    const float* bo  = (const float*)d_in[10];
    float* out = (float*)d_out;

    char* ws = (char*)d_ws;
    unsigned short* Wt  = (unsigned short*)(ws);
    float*          bqs = (float*)(ws + 8388608);
    unsigned short* Qb  = (unsigned short*)(ws + 8392704);
    unsigned short* Kb  = (unsigned short*)(ws + 8392704 + 16777216);
    unsigned short* Vb  = (unsigned short*)(ws + 8392704 + 2 * 16777216);  // [b,h,hd,s]
    unsigned short* Xb  = (unsigned short*)(ws + 8392704 + 3 * 16777216);

    conv_w_kernel<<<dim3(16, 16, 4), 256, 0, stream>>>(Wq, Wk, Wv, Wo, bq, bqs, Wt);
    qkv_gemm_kernel<<<dim3(64, 8, 3), 256, 0, stream>>>(qin, kin, vin, Wt, bqs, bk, bv,
                                                        Qb, Kb, Vb);
    attn_kernel<<<dim3(16, 16, 4), 256, 0, stream>>>(Qb, Kb, Vb, Xb);
    out_gemm_kernel<<<dim3(64, 8), 256, 0, stream>>>(Xb, Wt + 3145728, bo, out);
}

// Round 22
// 200.036 us; speedup vs baseline: 1.2465x; 1.0081x over previous
//
#include <hip/hip_runtime.h>
#include <math.h>

constexpr int Bb = 4, Ss = 2048, Dd = 1024, Hh = 16, HDd = 64;

typedef __attribute__((ext_vector_type(8))) short short8;
typedef __attribute__((ext_vector_type(4))) float floatx4;
typedef __attribute__((ext_vector_type(16))) float floatx16;
typedef __attribute__((ext_vector_type(4))) unsigned int uint4v;

__device__ inline unsigned short bf16r(float f) {
    unsigned int u = __builtin_bit_cast(unsigned int, f);
    u += 0x7fffu + ((u >> 16) & 1u);
    return (unsigned short)(u >> 16);
}
// HW packed cvt (RNE, bit-identical to manual round)
__device__ inline unsigned int cvtpk(float lo, float hi) {
    unsigned int r;
    asm("v_cvt_pk_bf16_f32 %0, %1, %2" : "=v"(r) : "v"(lo), "v"(hi));
    return r;
}

__device__ inline void gld16(const void* g, void* l) {
    __builtin_amdgcn_global_load_lds((const __attribute__((address_space(1))) void*)g,
                                     (__attribute__((address_space(3))) void*)l, 16, 0, 0);
}

__device__ inline floatx4 mfma16(short8 a, short8 b, floatx4 c) {
    return __builtin_amdgcn_mfma_f32_16x16x32_bf16(a, b, c, 0, 0, 0);
}
__device__ inline floatx16 mfma32(short8 a, short8 b, floatx16 c) {
    return __builtin_amdgcn_mfma_f32_32x32x16_bf16(a, b, c, 0, 0, 0);
}

// log2(e) folded into Wq/bq so attn can use native exp2 directly.
#define LOG2E 1.4426950408889634f
#define EXP2_SHIFT 17.312340490667562f   // 12 * log2(e)

// ---------------------------------------------------------------------------
// Weight transpose + bf16 convert: Wt[z][n][k] = W_z[k][n] * scale_z.
// Block (0,0,z=0) additionally converts the q-bias (saves a launch).
// ---------------------------------------------------------------------------
__global__ __launch_bounds__(256)
void conv_w_kernel(const float* __restrict__ Wq, const float* __restrict__ Wk,
                   const float* __restrict__ Wv, const float* __restrict__ Wo,
                   const float* __restrict__ bq, float* __restrict__ bqs,
                   unsigned short* __restrict__ Wt)
{
    int z = blockIdx.z;
    const float* W = z == 0 ? Wq : z == 1 ? Wk : z == 2 ? Wv : Wo;
    float scale = z == 0 ? 0.125f * LOG2E : 1.0f;
    unsigned short* out = Wt + (size_t)z * 1024 * 1024;

    int r0 = blockIdx.x * 64;
    int c0 = blockIdx.y * 64;
    int t = threadIdx.x;
    int oc = (t & 3) * 16;
    int orow = c0 + (t >> 2);

    if (z == 0 && blockIdx.x == 0 && blockIdx.y == 0) {
        #pragma unroll
        for (int jj = 0; jj < 4; ++jj)
            bqs[t + jj * 256] = bq[t + jj * 256] * 0.125f * LOG2E;
    }

    float v[16];
    #pragma unroll
    for (int j = 0; j < 16; ++j)
        v[j] = W[(size_t)(r0 + oc + j) * 1024 + orow] * scale;

    unsigned int pk[8];
    #pragma unroll
    for (int j = 0; j < 8; ++j) pk[j] = cvtpk(v[2 * j], v[2 * j + 1]);

    uint4v w0 = {pk[0], pk[1], pk[2], pk[3]};
    uint4v w1 = {pk[4], pk[5], pk[6], pk[7]};
    *(uint4v*)(out + (size_t)orow * 1024 + r0 + oc) = w0;
    *(uint4v*)(out + (size_t)orow * 1024 + r0 + oc + 8) = w1;
}

// ---------------------------------------------------------------------------
// QKV projection GEMM v8 — v7 + 4-deep A pipeline (free at 2 blocks/CU):
//   A: raw fp32 gld_lds, FOUR buffers, issued 3 iterations ahead.
//   B: 2-stage gld_lds (L2-hot). Single barrier per kt.
//   Per iter: FV4(vmcnt(4) lgkmcnt(0); barrier) -> GLB(kt+1) ->
//             ISSUEA(kt+3) -> COMP(kt).
//   Race-free: overwrite of Aa[(kt+3)&3]=Aa[(kt-1)&3] follows the fence that
//   drained COMP(kt-1)'s reads (lgkmcnt(0)+barrier).
//   vmcnt: steady fence has {A(kt),A(kt+1),B(kt),A(kt+2)} outstanding in that
//   issue order; newer-than-B(kt) = A(kt+2) = 4 -> vmcnt(4). First fence:
//   {A0,B0,A1,A2} -> newer-than-B0 = 8 -> vmcnt(8). LDS = 80KB.
// ---------------------------------------------------------------------------
__global__ __launch_bounds__(256)
void qkv_gemm_kernel(const float* __restrict__ qin, const float* __restrict__ kin,
                     const float* __restrict__ vin,
                     const unsigned short* __restrict__ Wt,
                     const float* __restrict__ bqs, const float* __restrict__ bk,
                     const float* __restrict__ bv,
                     unsigned short* __restrict__ Qb, unsigned short* __restrict__ Kb,
                     unsigned short* __restrict__ Vb)
{
    int z = blockIdx.z;
    const float* A = z == 0 ? qin : z == 1 ? kin : vin;
    const unsigned short* W = Wt + (size_t)z * 1048576;
    const float* bias = z == 0 ? bqs : z == 1 ? bk : bv;
    unsigned short* O = z == 0 ? Qb : z == 1 ? Kb : Vb;

    __shared__ __align__(16) char qsm[81920];
    char* Aa0 = qsm;                 // A fp32 [128][32], swizzled, 16KB each
    char* Aa1 = qsm + 16384;
    char* Aa2 = qsm + 32768;
    char* Aa3 = qsm + 49152;
    char* Bb0 = qsm + 65536;         // B bf16 [128][32], linear, 8KB each
    char* Bb1 = qsm + 73728;

    int tid = threadIdx.x, lane = tid & 63, w = tid >> 6;
    int wr = w >> 1, wc = w & 1;
    int fr = lane & 15, fg = lane >> 4;
    int m0 = blockIdx.x * 128, n0 = blockIdx.y * 128;

    int arow_base = w * 32 + (lane >> 3);
    int asrc_col = (((lane & 7) ^ ((lane >> 3) & 7)) << 4) >> 2;  // fp32 elems
    const int bRdoB = ((wc * 64 + fr) * 32 + fg * 8) * 2;

    floatx4 acc[4][4] = {};

#define ISSUEA(kt, dst) {                                                       \
    _Pragma("unroll")                                                           \
    for (int j_ = 0; j_ < 4; ++j_) {                                            \
        const float* g_ = A + (size_t)(m0 + arow_base + j_ * 8) * 1024          \
                            + (kt) * 32 + asrc_col;                             \
        gld16(g_, (dst) + (size_t)((w << 8) + (j_ << 6) + lane) * 16);          \
    }}
#define GLB(kt, dst) {                                                          \
    const unsigned short* g0_ = W + (size_t)(n0 + (tid >> 2)) * 1024 + (kt) * 32 + (tid & 3) * 8;          \
    gld16(g0_, (dst) + (size_t)(w * 64) * 16);                                  \
    const unsigned short* g1_ = W + (size_t)(n0 + ((tid + 256) >> 2)) * 1024 + (kt) * 32 + (tid & 3) * 8;  \
    gld16(g1_, (dst) + (size_t)(256 + w * 64) * 16); }
#define COMP(Ac, Bc) { short8 af_[4], bf_[4];                                   \
    _Pragma("unroll")                                                           \
    for (int mi = 0; mi < 4; ++mi) {                                            \
        int row_ = wr * 64 + mi * 16 + fr;                                      \
        int xb_ = (row_ & 7) << 4;                                              \
        floatx4 al_ = *(const floatx4*)((Ac) + row_ * 128 + ((fg * 32) ^ xb_)); \
        floatx4 ah_ = *(const floatx4*)((Ac) + row_ * 128 + ((fg * 32 + 16) ^ xb_)); \
        uint4v u_ = {cvtpk(al_[0], al_[1]), cvtpk(al_[2], al_[3]),              \
                     cvtpk(ah_[0], ah_[1]), cvtpk(ah_[2], ah_[3])};             \
        af_[mi] = __builtin_bit_cast(short8, u_);                               \
    }                                                                           \
    _Pragma("unroll")                                                           \
    for (int ni = 0; ni < 4; ++ni) bf_[ni] = *(const short8*)((Bc) + bRdoB + ni * 1024); \
    _Pragma("unroll")                                                           \
    for (int mi = 0; mi < 4; ++mi)                                              \
        _Pragma("unroll")                                                       \
        for (int ni = 0; ni < 4; ++ni)                                          \
            acc[mi][ni] = mfma16(af_[mi], bf_[ni], acc[mi][ni]); }
#define FV8  { asm volatile("s_waitcnt vmcnt(8) lgkmcnt(0)" ::: "memory");      \
    __builtin_amdgcn_s_barrier(); __builtin_amdgcn_sched_barrier(0); }
#define FV4  { asm volatile("s_waitcnt vmcnt(4) lgkmcnt(0)" ::: "memory");      \
    __builtin_amdgcn_s_barrier(); __builtin_amdgcn_sched_barrier(0); }
#define FV0  { asm volatile("s_waitcnt vmcnt(0) lgkmcnt(0)" ::: "memory");      \
    __builtin_amdgcn_s_barrier(); __builtin_amdgcn_sched_barrier(0); }

    // prologue: A(0), B(0), A(1), A(2) in flight
    ISSUEA(0, Aa0); GLB(0, Bb0); ISSUEA(1, Aa1); ISSUEA(2, Aa2);

    // kt = 0 (first fence needs vmcnt(8): A1,A2 are newer than B0)
    FV8; GLB(1, Bb1); ISSUEA(3, Aa3); COMP(Aa0, Bb0);

    // main loop: kt = 1..28 (7 x 4); issue targets A(kt+3) <= 31, B(kt+1) <= 29
    for (int p = 0; p < 7; ++p) {
        int kt = 4 * p;   // body covers kt+1 .. kt+4
        FV4; GLB(kt + 2, Bb0); ISSUEA(kt + 4, Aa0); COMP(Aa1, Bb1);   // kt+1
        FV4; GLB(kt + 3, Bb1); ISSUEA(kt + 5, Aa1); COMP(Aa2, Bb0);   // kt+2
        FV4; GLB(kt + 4, Bb0); ISSUEA(kt + 6, Aa2); COMP(Aa3, Bb1);   // kt+3
        FV4; GLB(kt + 5, Bb1); ISSUEA(kt + 7, Aa3); COMP(Aa0, Bb0);   // kt+4
    }

    // epilogue: kt = 29, 30, 31
    FV4; GLB(30, Bb0); COMP(Aa1, Bb1);   // kt=29 (A(31) newer than B(29))
    FV0; GLB(31, Bb1); COMP(Aa2, Bb0);   // kt=30
    FV0; COMP(Aa3, Bb1);                 // kt=31
    __syncthreads();

#undef ISSUEA
#undef GLB
#undef COMP
#undef FV8
#undef FV4
#undef FV0

    float bvv[4];
    #pragma unroll
    for (int ni = 0; ni < 4; ++ni) bvv[ni] = bias[n0 + wc * 64 + ni * 16 + fr];

    if (z == 2) {
        // Per-wave transpose tile T[64 hd][72 pad] bf16, reusing staging LDS.
        unsigned short* T = (unsigned short*)(qsm) + (size_t)w * 4608;
        #pragma unroll
        for (int mi = 0; mi < 4; ++mi)
            #pragma unroll
            for (int ni = 0; ni < 4; ++ni) {
                int hdl = ni * 16 + fr;
                int sl  = mi * 16 + fg * 4;
                uint2 u2;
                u2.x = cvtpk(acc[mi][ni][0] + bvv[ni], acc[mi][ni][1] + bvv[ni]);
                u2.y = cvtpk(acc[mi][ni][2] + bvv[ni], acc[mi][ni][3] + bvv[ni]);
                *(uint2*)(T + hdl * 72 + sl) = u2;
            }
        __syncthreads();
        int h  = (n0 + wc * 64) >> 6;
        int Ms = m0 + wr * 64;
        int b_ = Ms >> 11, sbase = Ms & 2047;
        unsigned short* Od = O + (((size_t)(b_ * 16 + h) * 64) << 11) + sbase;
        int rg = lane >> 3, sc = lane & 7;
        #pragma unroll
        for (int j = 0; j < 8; ++j) {
            int row = j * 8 + rg;
            uint4v t = *(const uint4v*)(T + row * 72 + sc * 8);
            *(uint4v*)(Od + ((size_t)row << 11) + sc * 8) = t;
        }
    } else {
        #pragma unroll
        for (int mi = 0; mi < 4; ++mi)
            #pragma unroll
            for (int ni = 0; ni < 4; ++ni) {
                int n = n0 + wc * 64 + ni * 16 + fr;
                int h = n >> 6, hd = n & 63;
                #pragma unroll
                for (int i = 0; i < 4; ++i) {
                    int m = m0 + wr * 64 + mi * 16 + fg * 4 + i;
                    int b_ = m >> 11, s = m & 2047;
                    float val = acc[mi][ni][i] + bvv[ni];
                    O[(((size_t)(b_ * 16 + h) * 2048 + s) << 6) + hd] = bf16r(val);
                }
            }
    }
}

// ---------------------------------------------------------------------------
// Flash attention + XCD-chunk remap (verified form, unchanged)
// ---------------------------------------------------------------------------
__global__ __launch_bounds__(256)
void attn_kernel(const unsigned short* __restrict__ Qb, const unsigned short* __restrict__ Kb,
                 const unsigned short* __restrict__ Vtb, unsigned short* __restrict__ Xb)
{
    __shared__ __align__(16) char smem[32768];

    int pphys = blockIdx.x + (blockIdx.y << 4) + (blockIdx.z << 8);   // 0..1023
    int L = (pphys & 7) * 128 + (pphys >> 3);
    int qt = L & 15;
    int h  = (L >> 4) & 15;
    int b  = L >> 8;

    int tid = threadIdx.x, lane = tid & 63, w = tid >> 6;
    int c = lane & 31, hi = lane >> 5;
    int q0 = qt * 128;
    size_t base = ((size_t)(b * 16 + h)) * 2048 * 64;
    const unsigned short* Qp = Qb + base + (size_t)(q0 + w * 32) * 64;
    const unsigned short* Kp = Kb + base;
    const unsigned short* Vp = Vtb + base;

    short8 qfr[4];
    #pragma unroll
    for (int ks = 0; ks < 4; ++ks)
        qfr[ks] = *(const short8*)(Qp + (size_t)c * 64 + ks * 16 + hi * 8);

    floatx16 acc_o[2] = {};
    floatx16 acc_l = {};
    uint4v onesu = {0x3F803F80u, 0x3F803F80u, 0x3F803F80u, 0x3F803F80u};
    short8 onesb = __builtin_bit_cast(short8, onesu);

    int p0 = tid & 7;
    int r0 = tid >> 3;
    int r1 = r0 + 32;
    int g0 = p0 ^ (r0 & 7);

    auto STAGE = [&](int kt, char* Kd, char* Vd) {
        gld16(Kp + ((size_t)(kt * 64 + r0) << 6) + g0 * 8, Kd + (size_t)tid * 16);
        gld16(Kp + ((size_t)(kt * 64 + r1) << 6) + g0 * 8, Kd + (size_t)(tid + 256) * 16);
        gld16(Vp + ((size_t)r0 << 11) + kt * 64 + g0 * 8, Vd + (size_t)tid * 16);
        gld16(Vp + ((size_t)r1 << 11) + kt * 64 + g0 * 8, Vd + (size_t)(tid + 256) * 16);
    };

    STAGE(0, smem, smem + 8192);
    __syncthreads();

    for (int kt = 0; kt < 32; ++kt) {
        char* Kl = smem + (kt & 1) * 16384;
        char* Vl = Kl + 8192;
        if (kt + 1 < 32) {
            char* Kn = smem + ((kt + 1) & 1) * 16384;
            STAGE(kt + 1, Kn, Kn + 8192);
        }

        #pragma unroll
        for (int kvt = 0; kvt < 2; ++kvt) {
            floatx16 st;
            #pragma unroll
            for (int r = 0; r < 16; ++r) st[r] = -EXP2_SHIFT;

            __builtin_amdgcn_s_setprio(1);
            #pragma unroll
            for (int ks = 0; ks < 4; ++ks) {
                int row = kvt * 32 + c;
                short8 kf = *(const short8*)(Kl + row * 128 +
                                             ((ks * 32 + hi * 16) ^ ((row & 7) << 4)));
                st = mfma32(kf, qfr[ks], st);
            }
            __builtin_amdgcn_s_setprio(0);

            float p[16];
            #pragma unroll
            for (int r = 0; r < 16; ++r)
                p[r] = __builtin_amdgcn_exp2f(st[r]);
            unsigned int j[8];
            #pragma unroll
            for (int t2 = 0; t2 < 8; ++t2)
                j[t2] = cvtpk(p[2 * t2], p[2 * t2 + 1]);
            asm volatile("v_permlane32_swap_b32 %0, %1" : "+v"(j[0]), "+v"(j[2]));
            asm volatile("v_permlane32_swap_b32 %0, %1" : "+v"(j[1]), "+v"(j[3]));
            asm volatile("v_permlane32_swap_b32 %0, %1" : "+v"(j[4]), "+v"(j[6]));
            asm volatile("v_permlane32_swap_b32 %0, %1" : "+v"(j[5]), "+v"(j[7]));
            uint4v pa0 = {j[0], j[1], j[2], j[3]};
            uint4v pa1 = {j[4], j[5], j[6], j[7]};
            short8 paA = __builtin_bit_cast(short8, pa0);
            short8 paB = __builtin_bit_cast(short8, pa1);

            __builtin_amdgcn_s_setprio(1);
            #pragma unroll
            for (int kvs2 = 0; kvs2 < 2; ++kvs2) {
                int kstep = kvt * 2 + kvs2;
                short8 pa = kvs2 ? paB : paA;
                #pragma unroll
                for (int dvt = 0; dvt < 2; ++dvt) {
                    int dv = dvt * 32 + c;
                    short8 vf = *(const short8*)(Vl + dv * 128 +
                                                 ((kstep * 32 + hi * 16) ^ ((dv & 7) << 4)));
                    acc_o[dvt] = mfma32(pa, vf, acc_o[dvt]);
                }
            }
            acc_l = mfma32(paA, onesb, acc_l);
            acc_l = mfma32(paB, onesb, acc_l);
            __builtin_amdgcn_s_setprio(0);
        }
        __syncthreads();
    }

    unsigned short* Ot = (unsigned short*)smem;

    #pragma unroll
    for (int r = 0; r < 16; ++r) {
        int rowq = (r & 3) + 8 * (r >> 2) + 4 * hi;
        float inv = 1.0f / acc_l[r];
        int ql = w * 32 + rowq;
        Ot[ql * 64 + c]      = bf16r(acc_o[0][r] * inv);
        Ot[ql * 64 + 32 + c] = bf16r(acc_o[1][r] * inv);
    }
    __syncthreads();

    {
        int row = tid >> 1, half = tid & 1;
        const unsigned short* src = Ot + row * 64 + half * 32;
        unsigned short* dst = Xb + ((size_t)b * 2048 + q0 + row) * 1024
                                 + h * 64 + half * 32;
        uint4v v0 = *(const uint4v*)(src);
        uint4v v1 = *(const uint4v*)(src + 8);
        uint4v v2 = *(const uint4v*)(src + 16);
        uint4v v3 = *(const uint4v*)(src + 24);
        *(uint4v*)(dst) = v0;
        *(uint4v*)(dst + 8) = v1;
        *(uint4v*)(dst + 16) = v2;
        *(uint4v*)(dst + 24) = v3;
    }
}

// ---------------------------------------------------------------------------
// Output projection GEMM (unchanged)
// ---------------------------------------------------------------------------
__global__ __launch_bounds__(256)
void out_gemm_kernel(const unsigned short* __restrict__ Xb,
                     const unsigned short* __restrict__ Wto,
                     const float* __restrict__ bo, float* __restrict__ out)
{
    __shared__ __align__(16) char osm[32768];
    unsigned short* Asm0 = (unsigned short*)(osm);
    unsigned short* Bsm0 = (unsigned short*)(osm + 8192);
    unsigned short* Asm1 = (unsigned short*)(osm + 16384);
    unsigned short* Bsm1 = (unsigned short*)(osm + 24576);

    int tid = threadIdx.x, lane = tid & 63, w = tid >> 6;
    int wr = w >> 1, wc = w & 1;
    int fr = lane & 15, fg = lane >> 4;
    int m0 = blockIdx.x * 128, n0 = blockIdx.y * 128;

    const int aRdo = (wr * 64 + fr) * 32 + fg * 8;
    const int bRdo = (wc * 64 + fr) * 32 + fg * 8;

    floatx4 acc[4][4] = {};

    auto STAGE = [&](int k0, unsigned short* Ad, unsigned short* Bd) {
        #pragma unroll
        for (int it = 0; it < 2; ++it) {
            int cA = tid + it * 256;
            const unsigned short* ga = Xb + (size_t)(m0 + (cA >> 2)) * 1024 + k0 + (cA & 3) * 8;
            gld16(ga, (char*)Ad + (size_t)(it * 256 + w * 64) * 16);
            const unsigned short* gb = Wto + (size_t)(n0 + (cA >> 2)) * 1024 + k0 + (cA & 3) * 8;
            gld16(gb, (char*)Bd + (size_t)(it * 256 + w * 64) * 16);
        }
    };

    STAGE(0, Asm0, Bsm0);
    __syncthreads();

    for (int kt = 0; kt < 32; ++kt) {
        unsigned short* Acur = (kt & 1) ? Asm1 : Asm0;
        unsigned short* Bcur = (kt & 1) ? Bsm1 : Bsm0;
        if (kt < 31)
            STAGE((kt + 1) * 32, (kt & 1) ? Asm0 : Asm1, (kt & 1) ? Bsm0 : Bsm1);

        short8 af[4], bf[4];
        #pragma unroll
        for (int mi = 0; mi < 4; ++mi) af[mi] = *(const short8*)(Acur + aRdo + mi * 16 * 32);
        #pragma unroll
        for (int ni = 0; ni < 4; ++ni) bf[ni] = *(const short8*)(Bcur + bRdo + ni * 16 * 32);
        #pragma unroll
        for (int mi = 0; mi < 4; ++mi)
            #pragma unroll
            for (int ni = 0; ni < 4; ++ni)
                acc[mi][ni] = mfma16(af[mi], bf[ni], acc[mi][ni]);
        __syncthreads();
    }

    float bvv[4];
    #pragma unroll
    for (int ni = 0; ni < 4; ++ni) bvv[ni] = bo[n0 + wc * 64 + ni * 16 + fr];

    #pragma unroll
    for (int mi = 0; mi < 4; ++mi)
        #pragma unroll
        for (int ni = 0; ni < 4; ++ni) {
            int n = n0 + wc * 64 + ni * 16 + fr;
            #pragma unroll
            for (int i = 0; i < 4; ++i) {
                int m = m0 + wr * 64 + mi * 16 + fg * 4 + i;
                out[(size_t)m * 1024 + n] = acc[mi][ni][i] + bvv[ni];
            }
        }
}

// ---------------------------------------------------------------------------
extern "C" void kernel_launch(void* const* d_in, const int* in_sizes, int n_in,
                              void* d_out, int out_size, void* d_ws, size_t ws_size,
                              hipStream_t stream)
{
    const float* qin = (const float*)d_in[0];
    const float* kin = (const float*)d_in[1];
    const float* vin = (const float*)d_in[2];
    const float* Wq  = (const float*)d_in[3];
    const float* bq  = (const float*)d_in[4];
    const float* Wk  = (const float*)d_in[5];
    const float* bk  = (const float*)d_in[6];
    const float* Wv  = (const float*)d_in[7];
    const float* bv  = (const float*)d_in[8];
    const float* Wo  = (const float*)d_in[9];
    const float* bo  = (const float*)d_in[10];
    float* out = (float*)d_out;

    char* ws = (char*)d_ws;
    unsigned short* Wt  = (unsigned short*)(ws);
    float*          bqs = (float*)(ws + 8388608);
    unsigned short* Qb  = (unsigned short*)(ws + 8392704);
    unsigned short* Kb  = (unsigned short*)(ws + 8392704 + 16777216);
    unsigned short* Vb  = (unsigned short*)(ws + 8392704 + 2 * 16777216);  // [b,h,hd,s]
    unsigned short* Xb  = (unsigned short*)(ws + 8392704 + 3 * 16777216);

    conv_w_kernel<<<dim3(16, 16, 4), 256, 0, stream>>>(Wq, Wk, Wv, Wo, bq, bqs, Wt);
    qkv_gemm_kernel<<<dim3(64, 8, 3), 256, 0, stream>>>(qin, kin, vin, Wt, bqs, bk, bv,
                                                        Qb, Kb, Vb);
    attn_kernel<<<dim3(16, 16, 4), 256, 0, stream>>>(Qb, Kb, Vb, Xb);
    out_gemm_kernel<<<dim3(64, 8), 256, 0, stream>>>(Xb, Wt + 3145728, bo, out);
}